// Round 16
// baseline (285.665 us; speedup 1.0000x reference)
//
#include <hip/hip_runtime.h>
#include <hip/hip_bf16.h>
#include <cstdint>
#include <cstddef>

using f32x4 = __attribute__((ext_vector_type(4))) float;
using s16x8 = __attribute__((ext_vector_type(8))) short;
using s16x4 = __attribute__((ext_vector_type(4))) short;

#define DEVINL __device__ __forceinline__

static constexpr int T_LEN  = 2048;
static constexpr int MROWS  = 8192;   // B*T
static constexpr int NCHUNK = 32;     // T / 64

DEVINL float bf2f(short s){
  unsigned u = ((unsigned)(unsigned short)s) << 16;
  return __builtin_bit_cast(float, u);
}
DEVINL short f2bf(float f){
  unsigned u = __builtin_bit_cast(unsigned, f);
  u = (u + 0x7fffu + ((u >> 16) & 1u)) >> 16;
  return (short)(unsigned short)u;
}

// async global->LDS, 16B per lane; LDS dest must be wave-uniform base (+lane*16 implicit)
#define GLOAD16(gp, lp) \
  __builtin_amdgcn_global_load_lds((__attribute__((address_space(1))) void*)(gp), \
                                   (__attribute__((address_space(3))) void*)(lp), 16, 0, 0)

#define MFMA16(a, b, c) __builtin_amdgcn_mfma_f32_16x16x32_bf16((a), (b), (c), 0, 0, 0)
#define SBAR()  __builtin_amdgcn_sched_barrier(0)
#define WAITVM(n)   asm volatile("s_waitcnt vmcnt(" #n ")" ::: "memory")

// ---------------- elementwise f32 -> bf16 ----------------
__global__ __launch_bounds__(256) void cvt_f32_bf16(const float* __restrict__ in,
                                                    short* __restrict__ out, int n4){
  int i = blockIdx.x * 256 + threadIdx.x;
  if (i >= n4) return;
  float4 v = ((const float4*)in)[i];
  short4 o;
  o.x = f2bf(v.x); o.y = f2bf(v.y); o.z = f2bf(v.z); o.w = f2bf(v.w);
  ((short4*)out)[i] = o;
}

// ---------------- transpose f32 [R][C] -> bf16 [C][R] ----------------
__global__ __launch_bounds__(256) void tr_w(const float* __restrict__ in,
                                            short* __restrict__ out, int R, int C){
  __shared__ float tile[32][33];
  int c0 = blockIdx.x * 32, r0 = blockIdx.y * 32;
  int tx = threadIdx.x, ty = threadIdx.y;           // (32,8)
  #pragma unroll
  for (int i = 0; i < 4; ++i){
    int r = ty + i * 8;
    tile[r][tx] = in[(size_t)(r0 + r) * C + c0 + tx];
  }
  __syncthreads();
  #pragma unroll
  for (int i = 0; i < 4; ++i){
    int c = ty + i * 8;
    out[(size_t)(c0 + c) * R + r0 + tx] = f2bf(tile[tx][c]);
  }
}

// --------- merged transpose of the 4 projection weights into WT (q|k|g|v), all R=1024 ---------
__global__ __launch_bounds__(256) void tr_w4(const float* __restrict__ Wq,
                                             const float* __restrict__ Wk,
                                             const float* __restrict__ Wv,
                                             const float* __restrict__ Wg,
                                             short* __restrict__ WT){
  __shared__ float tile[32][33];
  int bx = blockIdx.x;
  const float* src; int C; size_t off; int cb;
  if (bx < 32)       { src = Wq; C = 1024; off = 0;                       cb = bx; }
  else if (bx < 64)  { src = Wk; C = 1024; off = (size_t)1024 * 1024;     cb = bx - 32; }
  else if (bx < 128) { src = Wg; C = 2048; off = (size_t)2048 * 1024;     cb = bx - 64; }
  else               { src = Wv; C = 2048; off = (size_t)4096 * 1024;     cb = bx - 128; }
  int c0 = cb * 32, r0 = blockIdx.y * 32;
  int tx = threadIdx.x, ty = threadIdx.y;           // (32,8)
  #pragma unroll
  for (int i = 0; i < 4; ++i){
    int r = ty + i * 8;
    tile[r][tx] = src[(size_t)(r0 + r) * C + c0 + tx];
  }
  __syncthreads();
  #pragma unroll
  for (int i = 0; i < 4; ++i){
    int c = ty + i * 8;
    WT[off + (size_t)(c0 + c) * 1024 + r0 + tx] = f2bf(tile[tx][c]);
  }
}

// ---------------- rope cos/sin table [2048][64] float2 ----------------
__global__ __launch_bounds__(256) void rope_table(float* __restrict__ tab){
  int i = blockIdx.x * 256 + threadIdx.x;           // t*64+d, 131072 total
  int t = i >> 6, d = i & 63;
  float inv = exp2f(-(float)d * (13.287712379549449f / 64.0f));  // 10000^(-d/64)
  float f = (float)t * inv;
  float s, c;
  sincosf(f, &s, &c);
  tab[2 * i]     = c;
  tab[2 * i + 1] = s;
}

// ------- RoPE in-place on q; bakes DK^-0.5 * gamma^((t%64)+1) -------
__global__ __launch_bounds__(256) void rope_q(short* __restrict__ qb,
                                              const float* __restrict__ tab){
  int idx = blockIdx.x * 256 + threadIdx.x;         // 8192 * 512 threads
  int bt  = idx >> 9, rem = idx & 511;
  int h   = rem >> 6, d = rem & 63;
  int t   = bt & (T_LEN - 1);
  float2 cs = ((const float2*)tab)[t * 64 + d];
  float lg = log2f(1.0f - exp2f(-(float)(5 + h)));
  float mult = 0.08838834764831845f * exp2f((float)((t & 63) + 1) * lg);  // DK^-0.5 * gamma^(i+1)
  size_t base = (size_t)bt * 1024 + h * 128 + d;
  float x1 = bf2f(qb[base]), x2 = bf2f(qb[base + 64]);
  qb[base]      = f2bf((x1 * cs.x - x2 * cs.y) * mult);
  qb[base + 64] = f2bf((x2 * cs.x + x1 * cs.y) * mult);
}

// ------- fused RoPE(k) in-place + decay-baked transpose kb -> kTt [1024][8192] -------
// grid (128 bt-chunks, 8 heads), 256 thr. Tile = 64 bt rows x 128 d cols (one head).
__global__ __launch_bounds__(256) void rope_k_tr(short* __restrict__ kb,
                                                 short* __restrict__ kTt,
                                                 const float* __restrict__ tab){
  __shared__ alignas(16) short T[64 * 128];          // staging tile [r][d]
  __shared__ alignas(16) short U[128 * 68];          // transposed [d][r], ld 68 (bank spread)
  const int tid = threadIdx.x, wave = tid >> 6, lane = tid & 63;
  const int bt0 = blockIdx.x * 64, h = blockIdx.y;
  const float lg = log2f(1.0f - exp2f(-(float)(5 + h)));
  // ---- stage: 64 rows x 256B, 4 gload calls (linear dest)
  #pragma unroll
  for (int c = 0; c < 4; ++c){
    int rbase = c * 16 + wave * 4;
    GLOAD16(kb + (size_t)(bt0 + rbase + (lane >> 4)) * 1024 + h * 128 + (lane & 15) * 8,
            T + rbase * 128);
  }
  WAITVM(0);
  __syncthreads();
  // ---- rope: thread owns (r = tid>>2, d in [ (tid&3)*16, +16 )); writes kb + U
  {
    int r = tid >> 2, dbase = (tid & 3) * 16;
    int t = (bt0 + r) & (T_LEN - 1);
    float dec = exp2f((float)(63 - r) * lg);
    s16x8 lo[2], hi[2];
    #pragma unroll
    for (int i = 0; i < 16; ++i){
      int d = dbase + i;
      float2 cs = ((const float2*)tab)[t * 64 + d];
      float x1 = bf2f(T[r * 128 + d]);
      float x2 = bf2f(T[r * 128 + 64 + d]);
      float y1 = x1 * cs.x - x2 * cs.y;
      float y2 = x2 * cs.x + x1 * cs.y;
      lo[i >> 3][i & 7] = f2bf(y1);
      hi[i >> 3][i & 7] = f2bf(y2);
      U[(d)      * 68 + r] = f2bf(y1 * dec);
      U[(d + 64) * 68 + r] = f2bf(y2 * dec);
    }
    size_t gb = (size_t)(bt0 + r) * 1024 + h * 128 + dbase;
    *(s16x8*)&kb[gb]          = lo[0];
    *(s16x8*)&kb[gb + 8]      = lo[1];
    *(s16x8*)&kb[gb + 64]     = hi[0];
    *(s16x8*)&kb[gb + 64 + 8] = hi[1];
  }
  __syncthreads();
  // ---- kTt write: thread owns (d = tid>>1, half = tid&1): 32 bt contiguous (64B)
  {
    int d = tid >> 1, half = tid & 1;
    const short* src = &U[d * 68 + half * 32];
    size_t gb = (size_t)(h * 128 + d) * MROWS + bt0 + half * 32;
    #pragma unroll
    for (int c = 0; c < 8; ++c)
      *(s16x4*)&kTt[gb + c * 4] = *(const s16x4*)&src[c * 4];
  }
}

// ======= half-tile GEMM: BK=64, 8 waves, 2 raw barriers/tile, compiler-scheduled ds_reads =======
// C[m][n] = sum_k A[m][k] * Bt[n][k].
// MODE 3: BM=256, swapped operands, q|k|g bf16 row-major packed s16x4 stores (N=4096).
// MODE 4: BM=256, normal operands, v transposed out [2048][8192] packed s16x4 col stores, o2.
DEVINL s16x8 frag64(const short* buf, int row, int ks, int lhi){
  int ch = (ks * 4 + lhi) ^ (row & 7);
  return *(const s16x8*)&buf[row * 64 + ch * 8];
}

template<int MODE>
__global__ __launch_bounds__(512, 2) void gemm256(const short* __restrict__ A,
                                                  const short* __restrict__ Bt,
                                                  void* __restrict__ o0, void* __restrict__ o1,
                                                  void* __restrict__ o2, void* __restrict__ o3,
                                                  int K, int nt, int NT){
  constexpr int BM   = 256;
  constexpr int ABUF = BM * 64;                     // shorts per A buffer
  constexpr int MF   = BM / 32;                     // acc rows per wave (8)
  constexpr int MH   = MF / 2;                      // acc rows per half (4)
  __shared__ alignas(16) short LBUF[3 * ABUF + 2 * 16384];
  short* const BB = LBUF + 3 * ABUF;
  const int tid = threadIdx.x, wave = tid >> 6, lane = tid & 63;
  const int l15 = lane & 15, lhi = lane >> 4;
  const int wm = (wave >> 2) * (BM / 2), wn = (wave & 3) * 64;
  // XCD group-major swizzle: per XCD walk m within group of MG (A stays L2-resident), n outer
  const int MG  = (gridDim.x >> 3) / NT;
  const int xcd = blockIdx.x & 7, idx = blockIdx.x >> 3;
  const int mi  = idx % MG, nn = idx / MG;
  const int m0  = (xcd * MG + mi) * BM, n0 = nn * 256;
  const short* Ag = A + (size_t)m0 * K;
  const short* Bg = Bt + (size_t)n0 * K;
  const int sr = lane >> 3;
  const int gc = ((lane & 7) ^ sr) * 8;             // pre-swizzled source chunk
  f32x4 acc[MF][4] = {};

  auto stageA = [&](int t, int half){
    short* lb = LBUF + (t % 3) * ABUF;
    size_t k0 = (size_t)t * 64;
    #pragma unroll
    for (int c = 0; c < 2; ++c){
      int r0 = half * 128 + c * 64;
      GLOAD16(Ag + (size_t)(r0 + wave * 8 + sr) * K + k0 + gc, lb + (r0 + wave * 8) * 64);
    }
  };
  auto stageB = [&](int t, int half){
    short* lb = BB + (t & 1) * 16384;
    size_t k0 = (size_t)t * 64;
    #pragma unroll
    for (int c = 0; c < 2; ++c){
      int r0 = half * 128 + c * 64;
      GLOAD16(Bg + (size_t)(r0 + wave * 8 + sr) * K + k0 + gc, lb + (r0 + wave * 8) * 64);
    }
  };

  // ---- prologue: stage tiles 0 and 1; drain tile0, keep tile1 in flight
  stageA(0, 0); stageA(0, 1); stageB(0, 0); stageB(0, 1);
  stageA(1, 0); stageA(1, 1); stageB(1, 0); stageB(1, 1);
  WAITVM(8);
  __builtin_amdgcn_s_barrier();

  for (int t = 0; t < nt; ++t){
    const short* Ab = LBUF + (t % 3) * ABUF;
    const short* Bb = BB + (t & 1) * 16384;
    s16x8 bfr[2][4];
    s16x8 af[MH][2];
    // ---- first half: read B (whole tile) + A rows [0, MH); MFMA overlaps read drain
    #pragma unroll
    for (int ks = 0; ks < 2; ++ks)
      #pragma unroll
      for (int nf = 0; nf < 4; ++nf)
        bfr[ks][nf] = frag64(Bb, wn + nf * 16 + l15, ks, lhi);
    #pragma unroll
    for (int i = 0; i < MH; ++i)
      #pragma unroll
      for (int ks = 0; ks < 2; ++ks)
        af[i][ks] = frag64(Ab, wm + i * 16 + l15, ks, lhi);
    if (t + 2 < nt){ stageA(t + 2, 0); stageA(t + 2, 1); }
    __builtin_amdgcn_s_setprio(1);
    #pragma unroll
    for (int ks = 0; ks < 2; ++ks)
      #pragma unroll
      for (int i = 0; i < MH; ++i)
        #pragma unroll
        for (int nf = 0; nf < 4; ++nf){
          if constexpr (MODE == 4)
            acc[i][nf] = MFMA16(af[i][ks], bfr[ks][nf], acc[i][nf]);
          else
            acc[i][nf] = MFMA16(bfr[ks][nf], af[i][ks], acc[i][nf]);
        }
    __builtin_amdgcn_s_setprio(0);
    __builtin_amdgcn_s_barrier();                   // mid: all waves' B(t)/A-half0 regs populated
    // ---- second half: stageB(t+2) now safe; read A rows [MH, MF)
    if (t + 2 < nt){ stageB(t + 2, 0); stageB(t + 2, 1); }
    #pragma unroll
    for (int i = 0; i < MH; ++i)
      #pragma unroll
      for (int ks = 0; ks < 2; ++ks)
        af[i][ks] = frag64(Ab, wm + (MH + i) * 16 + l15, ks, lhi);
    __builtin_amdgcn_s_setprio(1);
    #pragma unroll
    for (int ks = 0; ks < 2; ++ks)
      #pragma unroll
      for (int i = 0; i < MH; ++i)
        #pragma unroll
        for (int nf = 0; nf < 4; ++nf){
          if constexpr (MODE == 4)
            acc[MH + i][nf] = MFMA16(af[i][ks], bfr[ks][nf], acc[MH + i][nf]);
          else
            acc[MH + i][nf] = MFMA16(bfr[ks][nf], af[i][ks], acc[MH + i][nf]);
        }
    __builtin_amdgcn_s_setprio(0);
    if (t < nt - 2){
      WAITVM(8);                                    // t+1 fully landed
    } else if (t == nt - 2){
      WAITVM(0);
    }
    __builtin_amdgcn_s_barrier();                   // end: tile t+1 visible to all
  }
  // ---- epilogue (packed stores)
  if constexpr (MODE == 4){
    // normal order: v transposed out [2048][8192]; lane's 4 accs = 4 consecutive rows
    short* dst = (short*)o2;
    #pragma unroll
    for (int mf = 0; mf < MF; ++mf){
      int rb = m0 + wm + mf * 16 + 4 * lhi;
      #pragma unroll
      for (int nf = 0; nf < 4; ++nf){
        int e = n0 + wn + nf * 16 + l15;
        s16x4 pk;
        #pragma unroll
        for (int r = 0; r < 4; ++r) pk[r] = f2bf(acc[mf][nf][r]);
        *(s16x4*)&dst[(size_t)e * MROWS + rb] = pk;
      }
    }
  } else {
    // swapped: q/k/g row-major; lane's 4 accs = 4 consecutive cols of one row
    short* dst; int ld, cb;
    if (n0 < 1024)      { dst = (short*)o0; ld = 1024; cb = n0; }
    else if (n0 < 2048) { dst = (short*)o1; ld = 1024; cb = n0 - 1024; }
    else                { dst = (short*)o3; ld = 2048; cb = n0 - 2048; }
    #pragma unroll
    for (int mf = 0; mf < MF; ++mf){
      int m = m0 + wm + mf * 16 + l15;
      #pragma unroll
      for (int nf = 0; nf < 4; ++nf){
        int nb = cb + wn + nf * 16 + 4 * lhi;
        s16x4 pk;
        #pragma unroll
        for (int r = 0; r < 4; ++r) pk[r] = f2bf(acc[mf][nf][r]);
        *(s16x4*)&dst[(size_t)m * ld + nb] = pk;
      }
    }
  }
}

// ======= round-3 style 128x128x(BK=64) bt-GEMM, f32 out (small LDS -> multi-block/CU) =======
// C[m][n] = sum_k A[m][k]*Bt[n][k]; out f32 [M][N]. Measured 52.9us on the out-projection shape.
__global__ __launch_bounds__(256) void gemm_bt_f32(const short* __restrict__ A,
                                                   const short* __restrict__ Bt,
                                                   float* __restrict__ out, int K, int N){
  __shared__ alignas(16) short As[128 * 64];
  __shared__ alignas(16) short Bs[128 * 64];
  const int tid = threadIdx.x, wave = tid >> 6, lane = tid & 63;
  const int m0 = blockIdx.x * 128, n0 = blockIdx.y * 128;
  const int wm = (wave & 1) * 64, wn = (wave >> 1) * 64;
  f32x4 acc[4][4] = {};
  const int srow = wave * 8 + (lane >> 3);          // staging row-in-call (rows are 128B)
  const int sc   = lane & 7;                        // staging 16B-chunk within row
  const int kT = K >> 6;
  for (int kt = 0; kt < kT; ++kt){
    const int k0 = kt << 6;
    #pragma unroll
    for (int c = 0; c < 4; ++c){
      int row = c * 32 + srow;
      int gc  = sc ^ (row & 7);                     // pre-swizzled global source
      GLOAD16(A  + (size_t)(m0 + row) * K + k0 + gc * 8, &As[c * 2048 + wave * 512]);
      GLOAD16(Bt + (size_t)(n0 + row) * K + k0 + gc * 8, &Bs[c * 2048 + wave * 512]);
    }
    __syncthreads();
    #pragma unroll
    for (int ks = 0; ks < 2; ++ks){
      s16x8 af[4], bfr[4];
      #pragma unroll
      for (int mf = 0; mf < 4; ++mf){
        int row = wm + mf * 16 + (lane & 15);
        int ch  = (ks * 4 + (lane >> 4)) ^ (row & 7);
        af[mf] = *(const s16x8*)&As[row * 64 + ch * 8];
      }
      #pragma unroll
      for (int nf = 0; nf < 4; ++nf){
        int row = wn + nf * 16 + (lane & 15);
        int ch  = (ks * 4 + (lane >> 4)) ^ (row & 7);
        bfr[nf] = *(const s16x8*)&Bs[row * 64 + ch * 8];
      }
      #pragma unroll
      for (int mf = 0; mf < 4; ++mf)
        #pragma unroll
        for (int nf = 0; nf < 4; ++nf)
          acc[mf][nf] = MFMA16(af[mf], bfr[nf], acc[mf][nf]);
    }
    __syncthreads();
  }
  #pragma unroll
  for (int mf = 0; mf < 4; ++mf){
    #pragma unroll
    for (int nf = 0; nf < 4; ++nf){
      int col   = n0 + wn + nf * 16 + (lane & 15);
      int rbase = m0 + wm + mf * 16 + 4 * (lane >> 4);
      f32x4 v = acc[mf][nf];
      #pragma unroll
      for (int r = 0; r < 4; ++r) out[(size_t)(rbase + r) * N + col] = v[r];
    }
  }
}

// ---------------- retention state scan: S in MFMA accumulators, write bf16 ST[n] snapshots ----------------
// grid (8=db*eb, 8, 4); 256 thr. Block owns d-range 64 (db) x e-range 64 (eb).
__global__ __launch_bounds__(256) void ret_scan(const short* __restrict__ kT,
                                                const short* __restrict__ vT,
                                                short* __restrict__ ST){
  __shared__ alignas(16) short kbuf[3][4096];
  __shared__ alignas(16) short vbuf[3][4096];
  const int tid = threadIdx.x, wave = tid >> 6, lane = tid & 63;
  const int db = blockIdx.x & 1, eb = blockIdx.x >> 1;
  const int h = blockIdx.y, b = blockIdx.z;
  const int d0 = db * 64, e0 = eb * 64;
  const float lg = log2f(1.0f - exp2f(-(float)(5 + h)));
  const float gC = exp2f(64.0f * lg);
  f32x4 Sacc[4] = {};
  const int srow = wave * 8 + (lane >> 3);
  const int sc   = lane & 7;

  auto STAGE = [&](int n, int buf){
    size_t rowbase = (size_t)(b * T_LEN + n * 64);
    #pragma unroll
    for (int c = 0; c < 2; ++c){
      int r = c * 32 + srow;
      int gc2 = sc ^ (r & 7);
      GLOAD16(kT + (size_t)(h * 128 + d0 + r) * MROWS + rowbase + gc2 * 8,
              &kbuf[buf][c * 2048 + wave * 512]);
    }
    #pragma unroll
    for (int c = 0; c < 2; ++c){
      int r = c * 32 + srow;
      int gc2 = sc ^ (r & 7);
      GLOAD16(vT + (size_t)(h * 256 + e0 + r) * MROWS + rowbase + gc2 * 8,
              &vbuf[buf][c * 2048 + wave * 512]);
    }
  };

  STAGE(0, 0);
  STAGE(1, 1);
  for (int n = 0; n < NCHUNK; ++n){
    const int buf = n % 3;
    if (n + 2 < NCHUNK) STAGE(n + 2, (n + 2) % 3);      // 4 loads
    if (n > 0){                                          // 4 stores (snapshot BEFORE this chunk)
      size_t stb = (((size_t)n * 4 + b) * 8 + h) * 32768;
      int dbase = d0 + 16 * wave + 4 * (lane >> 4);
      #pragma unroll
      for (int nf = 0; nf < 4; ++nf){
        int e = e0 + nf * 16 + (lane & 15);
        s16x4 pk;
        #pragma unroll
        for (int r = 0; r < 4; ++r) pk[r] = f2bf(Sacc[nf][r]);
        *(s16x4*)&ST[stb + (size_t)e * 128 + dbase] = pk;
      }
    }
    // counted vmcnt: guarantee chunk-n loads complete; newer loads/stores stay outstanding
    if (n == 0)       WAITVM(8);
    else if (n < 30)  WAITVM(12);
    else if (n == 30) WAITVM(8);
    else              WAITVM(4);
    __builtin_amdgcn_s_barrier();
    SBAR();
    #pragma unroll
    for (int nf = 0; nf < 4; ++nf)
      #pragma unroll
      for (int r = 0; r < 4; ++r) Sacc[nf][r] *= gC;
    #pragma unroll
    for (int ks = 0; ks < 2; ++ks){
      int d = 16 * wave + (lane & 15);
      int chA = (ks * 4 + (lane >> 4)) ^ (d & 7);
      s16x8 af = *(const s16x8*)&kbuf[buf][d * 64 + chA * 8];
      #pragma unroll
      for (int nf = 0; nf < 4; ++nf){
        int e = nf * 16 + (lane & 15);
        int chB = (ks * 4 + (lane >> 4)) ^ (e & 7);
        s16x8 bv = *(const s16x8*)&vbuf[buf][e * 64 + chB * 8];
        Sacc[nf] = MFMA16(af, bv, Sacc[nf]);
      }
    }
    __builtin_amdgcn_s_barrier();
    SBAR();
  }
}

// ---------------- fused per-chunk retention + RMS-norm + SiLU gate (reg-direct) ----------------
__global__ __launch_bounds__(256, 2) void ret_fused(const short* __restrict__ q,
                                                    const short* __restrict__ k,
                                                    const short* __restrict__ vT,
                                                    const short* __restrict__ ST,
                                                    const short* __restrict__ g,
                                                    const float* __restrict__ nw,
                                                    short* __restrict__ y){
  __shared__ alignas(16) short GS[16384];             // gate tile [64][256]
  __shared__ alignas(16) float SS[256];               // cross-wave sum-of-squares
  __shared__ alignas(16) short XS[16896];             // phase1: PS [64][72]; phase2: YT [64][264]
  short* PS = XS;
  short* YT = XS;
  const int tid = threadIdx.x, wave = tid >> 6, lane = tid & 63;
  const int l15 = lane & 15, lhi = lane >> 4;
  const int n = blockIdx.x, h = blockIdx.y, b = blockIdx.z;
  const size_t rowbase = (size_t)(b * T_LEN + n * 64);
  // ---- issue gate staging first (consumed in epilogue; drained by syncthreads)
  {
    int row = wave * 2 + (lane >> 5), sc32 = lane & 31;
    #pragma unroll
    for (int c = 0; c < 8; ++c){
      int r = c * 8 + row;
      GLOAD16(g + (rowbase + r) * 2048 + h * 256 + sc32 * 8, &GS[c * 2048 + wave * 512]);
    }
  }
  // ---- Q fragments (reused as P-phase B-operand AND o_inter A-operand)
  s16x8 Qf[4][4];
  #pragma unroll
  for (int rf = 0; rf < 4; ++rf)
    #pragma unroll
    for (int ks = 0; ks < 4; ++ks)
      Qf[rf][ks] = *(const s16x8*)&q[(rowbase + rf * 16 + l15) * 1024 + h * 128 + ks * 32 + lhi * 8];
  // ---- K fragments (P-phase A-operand; wave-specific j rows)
  s16x8 Kf[4];
  #pragma unroll
  for (int ks = 0; ks < 4; ++ks)
    Kf[ks] = *(const s16x8*)&k[(rowbase + wave * 16 + l15) * 1024 + h * 128 + ks * 32 + lhi * 8];
  // ---- P^T = k q'^T : D[j][i]; wave owns j in [16w,16w+16)
  f32x4 accP[4] = {};
  #pragma unroll
  for (int ks = 0; ks < 4; ++ks)
    #pragma unroll
    for (int nf = 0; nf < 4; ++nf)
      accP[nf] = MFMA16(Kf[ks], Qf[nf][ks], accP[nf]);
  const float lg = log2f(1.0f - exp2f(-(float)(5 + h)));
  {
    int jb = wave * 16 + 4 * lhi;
    float dj[4];
    #pragma unroll
    for (int r = 0; r < 4; ++r) dj[r] = exp2f(-(float)(jb + r + 1) * lg);
    #pragma unroll
    for (int nf = 0; nf < 4; ++nf){
      int i = nf * 16 + l15;
      s16x4 pk;
      #pragma unroll
      for (int r = 0; r < 4; ++r)
        pk[r] = f2bf((i >= jb + r) ? accP[nf][r] * dj[r] : 0.0f);
      *(s16x4*)&PS[i * 72 + jb] = pk;
    }
  }
  // ---- o_inter: acc = q'.S (ST fragments streamed global->reg); wave owns e in [64w,64w+64)
  f32x4 acc[4][4] = {};
  if (n){
    size_t stb = (((size_t)n * 4 + b) * 8 + h) * 32768;
    #pragma unroll
    for (int ks = 0; ks < 4; ++ks){
      s16x8 Sf[4];
      #pragma unroll
      for (int nf = 0; nf < 4; ++nf){
        int e = wave * 64 + nf * 16 + l15;
        Sf[nf] = *(const s16x8*)&ST[stb + (size_t)e * 128 + ks * 32 + lhi * 8];
      }
      #pragma unroll
      for (int mf = 0; mf < 4; ++mf)
        #pragma unroll
        for (int nf = 0; nf < 4; ++nf)
          acc[mf][nf] = MFMA16(Qf[mf][ks], Sf[nf], acc[mf][nf]);
    }
  }
  // ---- hoist V fragment loads above the PS barrier (latency hides under barrier wait)
  s16x8 Vf[2][4];
  #pragma unroll
  for (int ks2 = 0; ks2 < 2; ++ks2)
    #pragma unroll
    for (int nf = 0; nf < 4; ++nf){
      int e = wave * 64 + nf * 16 + l15;
      Vf[ks2][nf] = *(const s16x8*)&vT[(size_t)(h * 256 + e) * MROWS + rowbase + ks2 * 32 + lhi * 8];
    }
  __syncthreads();                                   // PS visible (also drains GS staging)
  // ---- o_intra: acc += P v  (P from LDS, V from regs)
  #pragma unroll
  for (int ks2 = 0; ks2 < 2; ++ks2){
    s16x8 Pf[4];
    #pragma unroll
    for (int mf = 0; mf < 4; ++mf)
      Pf[mf] = *(const s16x8*)&PS[(mf * 16 + l15) * 72 + ks2 * 32 + lhi * 8];
    #pragma unroll
    for (int mf = 0; mf < 4; ++mf)
      #pragma unroll
      for (int nf = 0; nf < 4; ++nf)
        acc[mf][nf] = MFMA16(Pf[mf], Vf[ks2][nf], acc[mf][nf]);
  }
  // ---- row-wise sum of squares (over e=256): intra-wave shuffle + cross-wave LDS
  float ssp[4][4];
  #pragma unroll
  for (int mf = 0; mf < 4; ++mf)
    #pragma unroll
    for (int r = 0; r < 4; ++r){
      float s = 0.f;
      #pragma unroll
      for (int nf = 0; nf < 4; ++nf) s += acc[mf][nf][r] * acc[mf][nf][r];
      #pragma unroll
      for (int off = 8; off >= 1; off >>= 1) s += __shfl_xor(s, off, 64);
      ssp[mf][r] = s;
    }
  if (l15 == 0){
    #pragma unroll
    for (int mf = 0; mf < 4; ++mf)
      #pragma unroll
      for (int r = 0; r < 4; ++r){
        int row = mf * 16 + 4 * lhi + r;
        SS[row * 4 + wave] = ssp[mf][r];
      }
  }
  __syncthreads();                                   // SS + GS ready; PS dead (YT aliases it)
  // ---- normalize + gate, write padded y tile
  #pragma unroll
  for (int mf = 0; mf < 4; ++mf){
    float rr[4];
    #pragma unroll
    for (int r = 0; r < 4; ++r){
      int row = mf * 16 + 4 * lhi + r;
      f32x4 s4 = *(const f32x4*)&SS[row * 4];
      float tot = s4[0] + s4[1] + s4[2] + s4[3];
      rr[r] = __builtin_amdgcn_rsqf(tot * (1.0f / 256.0f) + 1e-5f);
    }
    #pragma unroll
    for (int nf = 0; nf < 4; ++nf){
      int e = wave * 64 + nf * 16 + l15;
      float nwe = nw[e];
      #pragma unroll
      for (int r = 0; r < 4; ++r){
        int row = mf * 16 + 4 * lhi + r;
        float gf = bf2f(GS[row * 256 + e]);
        float sig = __builtin_amdgcn_rcpf(1.0f + exp2f(gf * -1.4426950408889634f));
        YT[row * 264 + e] = f2bf(acc[mf][nf][r] * rr[r] * nwe * gf * sig);
      }
    }
  }
  __syncthreads();
  // ---- coalesced copy out
  #pragma unroll
  for (int it = 0; it < 8; ++it){
    int flat = it * 2048 + tid * 8;
    int row = flat >> 8, e = flat & 255;
    s16x8 v = *(const s16x8*)&YT[row * 264 + e];
    *(s16x8*)&y[(rowbase + row) * 2048 + h * 256 + e] = v;
  }
}

// ---------------- host ----------------
extern "C" void kernel_launch(void* const* d_in, const int* in_sizes, int n_in,
                              void* d_out, int out_size, void* d_ws, size_t ws_size,
                              hipStream_t stream){
  const float* x  = (const float*)d_in[0];
  const float* Wq = (const float*)d_in[1];
  const float* Wk = (const float*)d_in[2];
  const float* Wv = (const float*)d_in[3];
  const float* Wg = (const float*)d_in[4];
  const float* Wo = (const float*)d_in[5];
  const float* nw = (const float*)d_in[6];
  float* out = (float*)d_out;

  // workspace layout (208 MiB total).  WT order: q|k|g|v.
  // yb aliases [0, 32MB) = xb + WT + head of kTt — all dead before ret_fused writes it.
  // rope table aliases STb's n=0 slice (scan writes n>=1 only, fused reads n>=1 only).
  char* w = (char*)d_ws;
  short* xb  = (short*)w;               w += (size_t)8192 * 1024 * 2;   // 16 MB
  short* WT  = (short*)w;               w += (size_t)6144 * 1024 * 2;   // 12.6 MB (WqT|WkT|WgT|WvT)
  short* kTt = (short*)w;               w += (size_t)1024 * 8192 * 2;   // 16 MB (dead after ret_scan)
  short* qb  = (short*)w;               w += (size_t)8192 * 1024 * 2;   // 16 MB
  short* kb  = (short*)w;               w += (size_t)8192 * 1024 * 2;   // 16 MB
  short* vT  = (short*)w;               w += (size_t)2048 * 8192 * 2;   // 32 MB
  short* gb  = (short*)w;               w += (size_t)8192 * 2048 * 2;   // 32 MB
  short* STb = (short*)w;               w += (size_t)32 * 4 * 8 * 32768 * 2; // 64 MB
  short* WoT = (short*)w;               w += (size_t)1024 * 2048 * 2;   // 4 MB
  short* yb  = (short*)d_ws;                                            // alias, 32 MB
  float* tab = (float*)STb;                                             // alias, 1 MB (n=0 slice)

  cvt_f32_bf16<<<8192, 256, 0, stream>>>(x, xb, 8192 * 1024 / 4);
  dim3 tb(32, 8);
  tr_w4<<<dim3(192, 32), tb, 0, stream>>>(Wq, Wk, Wv, Wg, WT);
  tr_w <<<dim3(32, 64),  tb, 0, stream>>>(Wo, WoT, 2048, 1024);
  rope_table<<<512, 256, 0, stream>>>(tab);

  // q|k|g projection: [8192][1024] x [4096][1024]^T, swapped-operand packed stores
  gemm256<3><<<512, 512, 0, stream>>>(xb, WT, qb, kb, nullptr, gb, 1024, 16, 16);
  // v projection: [8192][1024] x [2048][1024]^T -> transposed vT [2048][8192]
  gemm256<4><<<256, 512, 0, stream>>>(xb, WT + (size_t)4096 * 1024, nullptr, nullptr, vT, nullptr,
                                      1024, 16, 8);

  rope_q   <<<16384, 256, 0, stream>>>(qb, tab);
  rope_k_tr<<<dim3(128, 8), 256, 0, stream>>>(kb, kTt, tab);

  ret_scan <<<dim3(8, 8, 4),  256, 0, stream>>>(kTt, vT, STb);
  ret_fused<<<dim3(32, 8, 4), 256, 0, stream>>>(qb, kb, vT, STb, gb, nw, yb);

  // out-projection: [8192][2048] x [1024][2048]^T -> f32 [8192][1024]
  // round-3 small-LDS 128^2 kernel: multi-block/CU residency beats the big-tile structure here
  gemm_bt_f32<<<dim3(64, 8), 256, 0, stream>>>(yb, WoT, out, 2048, 1024);
}

// Round 17
// 280.651 us; speedup vs baseline: 1.0179x; 1.0179x over previous
//
#include <hip/hip_runtime.h>
#include <hip/hip_bf16.h>
#include <cstdint>
#include <cstddef>

using f32x4 = __attribute__((ext_vector_type(4))) float;
using s16x8 = __attribute__((ext_vector_type(8))) short;
using s16x4 = __attribute__((ext_vector_type(4))) short;

#define DEVINL __device__ __forceinline__

static constexpr int T_LEN  = 2048;
static constexpr int MROWS  = 8192;   // B*T
static constexpr int NCHUNK = 32;     // T / 64

DEVINL float bf2f(short s){
  unsigned u = ((unsigned)(unsigned short)s) << 16;
  return __builtin_bit_cast(float, u);
}
DEVINL short f2bf(float f){
  unsigned u = __builtin_bit_cast(unsigned, f);
  u = (u + 0x7fffu + ((u >> 16) & 1u)) >> 16;
  return (short)(unsigned short)u;
}

// async global->LDS, 16B per lane; LDS dest must be wave-uniform base (+lane*16 implicit)
#define GLOAD16(gp, lp) \
  __builtin_amdgcn_global_load_lds((__attribute__((address_space(1))) void*)(gp), \
                                   (__attribute__((address_space(3))) void*)(lp), 16, 0, 0)

#define MFMA16(a, b, c) __builtin_amdgcn_mfma_f32_16x16x32_bf16((a), (b), (c), 0, 0, 0)
#define SBAR()  __builtin_amdgcn_sched_barrier(0)
#define WAITVM(n)   asm volatile("s_waitcnt vmcnt(" #n ")" ::: "memory")

// ---------------- elementwise f32 -> bf16 ----------------
__global__ __launch_bounds__(256) void cvt_f32_bf16(const float* __restrict__ in,
                                                    short* __restrict__ out, int n4){
  int i = blockIdx.x * 256 + threadIdx.x;
  if (i >= n4) return;
  float4 v = ((const float4*)in)[i];
  short4 o;
  o.x = f2bf(v.x); o.y = f2bf(v.y); o.z = f2bf(v.z); o.w = f2bf(v.w);
  ((short4*)out)[i] = o;
}

// ---------------- transpose f32 [R][C] -> bf16 [C][R] ----------------
__global__ __launch_bounds__(256) void tr_w(const float* __restrict__ in,
                                            short* __restrict__ out, int R, int C){
  __shared__ float tile[32][33];
  int c0 = blockIdx.x * 32, r0 = blockIdx.y * 32;
  int tx = threadIdx.x, ty = threadIdx.y;           // (32,8)
  #pragma unroll
  for (int i = 0; i < 4; ++i){
    int r = ty + i * 8;
    tile[r][tx] = in[(size_t)(r0 + r) * C + c0 + tx];
  }
  __syncthreads();
  #pragma unroll
  for (int i = 0; i < 4; ++i){
    int c = ty + i * 8;
    out[(size_t)(c0 + c) * R + r0 + tx] = f2bf(tile[tx][c]);
  }
}

// --------- merged transpose of the 4 projection weights into WT (q|k|g|v), all R=1024 ---------
__global__ __launch_bounds__(256) void tr_w4(const float* __restrict__ Wq,
                                             const float* __restrict__ Wk,
                                             const float* __restrict__ Wv,
                                             const float* __restrict__ Wg,
                                             short* __restrict__ WT){
  __shared__ float tile[32][33];
  int bx = blockIdx.x;
  const float* src; int C; size_t off; int cb;
  if (bx < 32)       { src = Wq; C = 1024; off = 0;                       cb = bx; }
  else if (bx < 64)  { src = Wk; C = 1024; off = (size_t)1024 * 1024;     cb = bx - 32; }
  else if (bx < 128) { src = Wg; C = 2048; off = (size_t)2048 * 1024;     cb = bx - 64; }
  else               { src = Wv; C = 2048; off = (size_t)4096 * 1024;     cb = bx - 128; }
  int c0 = cb * 32, r0 = blockIdx.y * 32;
  int tx = threadIdx.x, ty = threadIdx.y;           // (32,8)
  #pragma unroll
  for (int i = 0; i < 4; ++i){
    int r = ty + i * 8;
    tile[r][tx] = src[(size_t)(r0 + r) * C + c0 + tx];
  }
  __syncthreads();
  #pragma unroll
  for (int i = 0; i < 4; ++i){
    int c = ty + i * 8;
    WT[off + (size_t)(c0 + c) * 1024 + r0 + tx] = f2bf(tile[tx][c]);
  }
}

// ---------------- rope cos/sin table [2048][64] float2 ----------------
__global__ __launch_bounds__(256) void rope_table(float* __restrict__ tab){
  int i = blockIdx.x * 256 + threadIdx.x;           // t*64+d, 131072 total
  int t = i >> 6, d = i & 63;
  float inv = exp2f(-(float)d * (13.287712379549449f / 64.0f));  // 10000^(-d/64)
  float f = (float)t * inv;
  float s, c;
  sincosf(f, &s, &c);
  tab[2 * i]     = c;
  tab[2 * i + 1] = s;
}

// ------- RoPE in-place on q; bakes DK^-0.5 * gamma^((t%64)+1) -------
__global__ __launch_bounds__(256) void rope_q(short* __restrict__ qb,
                                              const float* __restrict__ tab){
  int idx = blockIdx.x * 256 + threadIdx.x;         // 8192 * 512 threads
  int bt  = idx >> 9, rem = idx & 511;
  int h   = rem >> 6, d = rem & 63;
  int t   = bt & (T_LEN - 1);
  float2 cs = ((const float2*)tab)[t * 64 + d];
  float lg = log2f(1.0f - exp2f(-(float)(5 + h)));
  float mult = 0.08838834764831845f * exp2f((float)((t & 63) + 1) * lg);  // DK^-0.5 * gamma^(i+1)
  size_t base = (size_t)bt * 1024 + h * 128 + d;
  float x1 = bf2f(qb[base]), x2 = bf2f(qb[base + 64]);
  qb[base]      = f2bf((x1 * cs.x - x2 * cs.y) * mult);
  qb[base + 64] = f2bf((x2 * cs.x + x1 * cs.y) * mult);
}

// ------- fused RoPE(k) in-place + decay-baked transpose kb -> kTt [1024][8192] -------
// grid (128 bt-chunks, 8 heads), 256 thr. Tile = 64 bt rows x 128 d cols (one head).
// kb gets roped values (no decay); kTt[(h*128+d)][bt] gets roped * gamma^(63-j), j = bt%64 = r.
__global__ __launch_bounds__(256) void rope_k_tr(short* __restrict__ kb,
                                                 short* __restrict__ kTt,
                                                 const float* __restrict__ tab){
  __shared__ alignas(16) short T[64 * 128];          // staging tile [r][d]
  __shared__ alignas(16) short U[128 * 68];          // transposed [d][r], ld 68 (bank spread)
  const int tid = threadIdx.x, wave = tid >> 6, lane = tid & 63;
  const int bt0 = blockIdx.x * 64, h = blockIdx.y;
  const float lg = log2f(1.0f - exp2f(-(float)(5 + h)));
  // ---- stage: 64 rows x 256B, 4 gload calls (linear dest)
  #pragma unroll
  for (int c = 0; c < 4; ++c){
    int rbase = c * 16 + wave * 4;
    GLOAD16(kb + (size_t)(bt0 + rbase + (lane >> 4)) * 1024 + h * 128 + (lane & 15) * 8,
            T + rbase * 128);
  }
  WAITVM(0);
  __syncthreads();
  // ---- rope: thread owns (r = tid>>2, d in [ (tid&3)*16, +16 )); writes kb + U
  {
    int r = tid >> 2, dbase = (tid & 3) * 16;
    int t = (bt0 + r) & (T_LEN - 1);
    float dec = exp2f((float)(63 - r) * lg);
    s16x8 lo[2], hi[2];
    #pragma unroll
    for (int i = 0; i < 16; ++i){
      int d = dbase + i;
      float2 cs = ((const float2*)tab)[t * 64 + d];
      float x1 = bf2f(T[r * 128 + d]);
      float x2 = bf2f(T[r * 128 + 64 + d]);
      float y1 = x1 * cs.x - x2 * cs.y;
      float y2 = x2 * cs.x + x1 * cs.y;
      lo[i >> 3][i & 7] = f2bf(y1);
      hi[i >> 3][i & 7] = f2bf(y2);
      U[(d)      * 68 + r] = f2bf(y1 * dec);
      U[(d + 64) * 68 + r] = f2bf(y2 * dec);
    }
    size_t gb = (size_t)(bt0 + r) * 1024 + h * 128 + dbase;
    *(s16x8*)&kb[gb]          = lo[0];
    *(s16x8*)&kb[gb + 8]      = lo[1];
    *(s16x8*)&kb[gb + 64]     = hi[0];
    *(s16x8*)&kb[gb + 64 + 8] = hi[1];
  }
  __syncthreads();
  // ---- kTt write: thread owns (d = tid>>1, half = tid&1): 32 bt contiguous (64B)
  {
    int d = tid >> 1, half = tid & 1;
    const short* src = &U[d * 68 + half * 32];
    size_t gb = (size_t)(h * 128 + d) * MROWS + bt0 + half * 32;
    #pragma unroll
    for (int c = 0; c < 8; ++c)
      *(s16x4*)&kTt[gb + c * 4] = *(const s16x4*)&src[c * 4];
  }
}

// ======= half-tile GEMM: BK=64, 8 waves, 2 raw barriers/tile, compiler-scheduled ds_reads =======
// C[m][n] = sum_k A[m][k] * Bt[n][k].
// Per tile: [rdB + rdA(half0) ; stageA(t+2) ; 32 MFMA ; s_barrier(mid) ; stageB(t+2) ;
//            rdA(half1) ; 32 MFMA ; vmcnt(counted) ; s_barrier(end)]
// MODE 2: BM=128, swapped operands, f32 row-major out (N=1024) -> float4 stores, o0.
// MODE 3: BM=256, swapped operands, q|k|g bf16 row-major packed s16x4 stores (N=4096).
// MODE 4: BM=256, normal operands, v transposed out [2048][8192] packed s16x4 col stores, o2.
DEVINL s16x8 frag64(const short* buf, int row, int ks, int lhi){
  int ch = (ks * 4 + lhi) ^ (row & 7);
  return *(const s16x8*)&buf[row * 64 + ch * 8];
}

template<int MODE>
__global__ __launch_bounds__(512, 2) void gemm256(const short* __restrict__ A,
                                                  const short* __restrict__ Bt,
                                                  void* __restrict__ o0, void* __restrict__ o1,
                                                  void* __restrict__ o2, void* __restrict__ o3,
                                                  int K, int nt, int NT){
  constexpr int BM   = (MODE == 2 ? 128 : 256);
  constexpr int ABUF = BM * 64;                     // shorts per A buffer
  constexpr int MF   = BM / 32;                     // acc rows per wave (4 or 8)
  constexpr int MH   = MF / 2;                      // acc rows per half (2 or 4)
  __shared__ alignas(16) short LBUF[3 * ABUF + 2 * 16384];
  short* const BB = LBUF + 3 * ABUF;
  const int tid = threadIdx.x, wave = tid >> 6, lane = tid & 63;
  const int l15 = lane & 15, lhi = lane >> 4;
  const int wm = (wave >> 2) * (BM / 2), wn = (wave & 3) * 64;
  // XCD group-major swizzle: per XCD walk m within group of MG (A stays L2-resident), n outer
  const int MG  = (gridDim.x >> 3) / NT;
  const int xcd = blockIdx.x & 7, idx = blockIdx.x >> 3;
  const int mi  = idx % MG, nn = idx / MG;
  const int m0  = (xcd * MG + mi) * BM, n0 = nn * 256;
  const short* Ag = A + (size_t)m0 * K;
  const short* Bg = Bt + (size_t)n0 * K;
  const int sr = lane >> 3;
  const int gc = ((lane & 7) ^ sr) * 8;             // pre-swizzled source chunk
  f32x4 acc[MF][4] = {};

  auto stageA = [&](int t, int half){
    short* lb = LBUF + (t % 3) * ABUF;
    size_t k0 = (size_t)t * 64;
    if constexpr (BM == 256){
      #pragma unroll
      for (int c = 0; c < 2; ++c){
        int r0 = half * 128 + c * 64;
        GLOAD16(Ag + (size_t)(r0 + wave * 8 + sr) * K + k0 + gc, lb + (r0 + wave * 8) * 64);
      }
    } else {
      int r0 = half * 64;
      GLOAD16(Ag + (size_t)(r0 + wave * 8 + sr) * K + k0 + gc, lb + (r0 + wave * 8) * 64);
    }
  };
  auto stageB = [&](int t, int half){
    short* lb = BB + (t & 1) * 16384;
    size_t k0 = (size_t)t * 64;
    #pragma unroll
    for (int c = 0; c < 2; ++c){
      int r0 = half * 128 + c * 64;
      GLOAD16(Bg + (size_t)(r0 + wave * 8 + sr) * K + k0 + gc, lb + (r0 + wave * 8) * 64);
    }
  };

  // ---- prologue: stage tiles 0 and 1; drain tile0, keep tile1 in flight
  stageA(0, 0); stageA(0, 1); stageB(0, 0); stageB(0, 1);
  stageA(1, 0); stageA(1, 1); stageB(1, 0); stageB(1, 1);
  if constexpr (BM == 256) WAITVM(8); else WAITVM(6);
  __builtin_amdgcn_s_barrier();

  for (int t = 0; t < nt; ++t){
    const short* Ab = LBUF + (t % 3) * ABUF;
    const short* Bb = BB + (t & 1) * 16384;
    s16x8 bfr[2][4];
    s16x8 af[MH][2];
    // ---- first half: read B (whole tile) + A rows [0, MH); MFMA overlaps read drain
    #pragma unroll
    for (int ks = 0; ks < 2; ++ks)
      #pragma unroll
      for (int nf = 0; nf < 4; ++nf)
        bfr[ks][nf] = frag64(Bb, wn + nf * 16 + l15, ks, lhi);
    #pragma unroll
    for (int i = 0; i < MH; ++i)
      #pragma unroll
      for (int ks = 0; ks < 2; ++ks)
        af[i][ks] = frag64(Ab, wm + i * 16 + l15, ks, lhi);
    if (t + 2 < nt){ stageA(t + 2, 0); stageA(t + 2, 1); }
    __builtin_amdgcn_s_setprio(1);
    #pragma unroll
    for (int ks = 0; ks < 2; ++ks)
      #pragma unroll
      for (int i = 0; i < MH; ++i)
        #pragma unroll
        for (int nf = 0; nf < 4; ++nf){
          if constexpr (MODE == 4)
            acc[i][nf] = MFMA16(af[i][ks], bfr[ks][nf], acc[i][nf]);
          else
            acc[i][nf] = MFMA16(bfr[ks][nf], af[i][ks], acc[i][nf]);
        }
    __builtin_amdgcn_s_setprio(0);
    __builtin_amdgcn_s_barrier();                   // mid: all waves' B(t)/A-half0 regs populated
    // ---- second half: stageB(t+2) now safe; read A rows [MH, MF)
    if (t + 2 < nt){ stageB(t + 2, 0); stageB(t + 2, 1); }
    #pragma unroll
    for (int i = 0; i < MH; ++i)
      #pragma unroll
      for (int ks = 0; ks < 2; ++ks)
        af[i][ks] = frag64(Ab, wm + (MH + i) * 16 + l15, ks, lhi);
    __builtin_amdgcn_s_setprio(1);
    #pragma unroll
    for (int ks = 0; ks < 2; ++ks)
      #pragma unroll
      for (int i = 0; i < MH; ++i)
        #pragma unroll
        for (int nf = 0; nf < 4; ++nf){
          if constexpr (MODE == 4)
            acc[MH + i][nf] = MFMA16(af[i][ks], bfr[ks][nf], acc[MH + i][nf]);
          else
            acc[MH + i][nf] = MFMA16(bfr[ks][nf], af[i][ks], acc[MH + i][nf]);
        }
    __builtin_amdgcn_s_setprio(0);
    if (t < nt - 2){
      if constexpr (BM == 256) WAITVM(8); else WAITVM(6);   // t+1 fully landed
    } else if (t == nt - 2){
      WAITVM(0);
    }
    __builtin_amdgcn_s_barrier();                   // end: tile t+1 visible to all
  }
  // ---- epilogue (packed stores)
  if constexpr (MODE == 2){
    // swapped: lane's 4 accs = 4 consecutive cols of one row -> float4
    float* dst = (float*)o0;
    #pragma unroll
    for (int mf = 0; mf < MF; ++mf){
      int m = m0 + wm + mf * 16 + l15;
      #pragma unroll
      for (int nf = 0; nf < 4; ++nf){
        int nb = n0 + wn + nf * 16 + 4 * lhi;
        *(float4*)&dst[(size_t)m * 1024 + nb] = *(float4*)&acc[mf][nf];
      }
    }
  } else if constexpr (MODE == 4){
    // normal order: v transposed out [2048][8192]; lane's 4 accs = 4 consecutive rows
    short* dst = (short*)o2;
    #pragma unroll
    for (int mf = 0; mf < MF; ++mf){
      int rb = m0 + wm + mf * 16 + 4 * lhi;
      #pragma unroll
      for (int nf = 0; nf < 4; ++nf){
        int e = n0 + wn + nf * 16 + l15;
        s16x4 pk;
        #pragma unroll
        for (int r = 0; r < 4; ++r) pk[r] = f2bf(acc[mf][nf][r]);
        *(s16x4*)&dst[(size_t)e * MROWS + rb] = pk;
      }
    }
  } else {
    // swapped: q/k/g row-major; lane's 4 accs = 4 consecutive cols of one row
    short* dst; int ld, cb;
    if (n0 < 1024)      { dst = (short*)o0; ld = 1024; cb = n0; }
    else if (n0 < 2048) { dst = (short*)o1; ld = 1024; cb = n0 - 1024; }
    else                { dst = (short*)o3; ld = 2048; cb = n0 - 2048; }
    #pragma unroll
    for (int mf = 0; mf < MF; ++mf){
      int m = m0 + wm + mf * 16 + l15;
      #pragma unroll
      for (int nf = 0; nf < 4; ++nf){
        int nb = cb + wn + nf * 16 + 4 * lhi;
        s16x4 pk;
        #pragma unroll
        for (int r = 0; r < 4; ++r) pk[r] = f2bf(acc[mf][nf][r]);
        *(s16x4*)&dst[(size_t)m * ld + nb] = pk;
      }
    }
  }
}

// ---------------- retention state scan: S in MFMA accumulators, write bf16 ST[n] snapshots ----------------
// grid (8=db*eb, 8, 4); 256 thr. Block owns d-range 64 (db) x e-range 64 (eb).
__global__ __launch_bounds__(256) void ret_scan(const short* __restrict__ kT,
                                                const short* __restrict__ vT,
                                                short* __restrict__ ST){
  __shared__ alignas(16) short kbuf[3][4096];
  __shared__ alignas(16) short vbuf[3][4096];
  const int tid = threadIdx.x, wave = tid >> 6, lane = tid & 63;
  const int db = blockIdx.x & 1, eb = blockIdx.x >> 1;
  const int h = blockIdx.y, b = blockIdx.z;
  const int d0 = db * 64, e0 = eb * 64;
  const float lg = log2f(1.0f - exp2f(-(float)(5 + h)));
  const float gC = exp2f(64.0f * lg);
  f32x4 Sacc[4] = {};
  const int srow = wave * 8 + (lane >> 3);
  const int sc   = lane & 7;

  auto STAGE = [&](int n, int buf){
    size_t rowbase = (size_t)(b * T_LEN + n * 64);
    #pragma unroll
    for (int c = 0; c < 2; ++c){
      int r = c * 32 + srow;
      int gc2 = sc ^ (r & 7);
      GLOAD16(kT + (size_t)(h * 128 + d0 + r) * MROWS + rowbase + gc2 * 8,
              &kbuf[buf][c * 2048 + wave * 512]);
    }
    #pragma unroll
    for (int c = 0; c < 2; ++c){
      int r = c * 32 + srow;
      int gc2 = sc ^ (r & 7);
      GLOAD16(vT + (size_t)(h * 256 + e0 + r) * MROWS + rowbase + gc2 * 8,
              &vbuf[buf][c * 2048 + wave * 512]);
    }
  };

  STAGE(0, 0);
  STAGE(1, 1);
  for (int n = 0; n < NCHUNK; ++n){
    const int buf = n % 3;
    if (n + 2 < NCHUNK) STAGE(n + 2, (n + 2) % 3);      // 4 loads
    if (n > 0){                                          // 4 stores (snapshot BEFORE this chunk)
      size_t stb = (((size_t)n * 4 + b) * 8 + h) * 32768;
      int dbase = d0 + 16 * wave + 4 * (lane >> 4);
      #pragma unroll
      for (int nf = 0; nf < 4; ++nf){
        int e = e0 + nf * 16 + (lane & 15);
        s16x4 pk;
        #pragma unroll
        for (int r = 0; r < 4; ++r) pk[r] = f2bf(Sacc[nf][r]);
        *(s16x4*)&ST[stb + (size_t)e * 128 + dbase] = pk;
      }
    }
    // counted vmcnt: guarantee chunk-n loads complete; newer loads/stores stay outstanding
    if (n == 0)       WAITVM(8);
    else if (n < 30)  WAITVM(12);
    else if (n == 30) WAITVM(8);
    else              WAITVM(4);
    __builtin_amdgcn_s_barrier();
    SBAR();
    #pragma unroll
    for (int nf = 0; nf < 4; ++nf)
      #pragma unroll
      for (int r = 0; r < 4; ++r) Sacc[nf][r] *= gC;
    #pragma unroll
    for (int ks = 0; ks < 2; ++ks){
      int d = 16 * wave + (lane & 15);
      int chA = (ks * 4 + (lane >> 4)) ^ (d & 7);
      s16x8 af = *(const s16x8*)&kbuf[buf][d * 64 + chA * 8];
      #pragma unroll
      for (int nf = 0; nf < 4; ++nf){
        int e = nf * 16 + (lane & 15);
        int chB = (ks * 4 + (lane >> 4)) ^ (e & 7);
        s16x8 bv = *(const s16x8*)&vbuf[buf][e * 64 + chB * 8];
        Sacc[nf] = MFMA16(af, bv, Sacc[nf]);
      }
    }
    __builtin_amdgcn_s_barrier();
    SBAR();
  }
}

// ---------------- fused per-chunk retention + RMS-norm + SiLU gate (reg-direct) ----------------
__global__ __launch_bounds__(256, 2) void ret_fused(const short* __restrict__ q,
                                                    const short* __restrict__ k,
                                                    const short* __restrict__ vT,
                                                    const short* __restrict__ ST,
                                                    const short* __restrict__ g,
                                                    const float* __restrict__ nw,
                                                    short* __restrict__ y){
  __shared__ alignas(16) short GS[16384];             // gate tile [64][256]
  __shared__ alignas(16) float SS[256];               // cross-wave sum-of-squares
  __shared__ alignas(16) short XS[16896];             // phase1: PS [64][72]; phase2: YT [64][264]
  short* PS = XS;
  short* YT = XS;
  const int tid = threadIdx.x, wave = tid >> 6, lane = tid & 63;
  const int l15 = lane & 15, lhi = lane >> 4;
  const int n = blockIdx.x, h = blockIdx.y, b = blockIdx.z;
  const size_t rowbase = (size_t)(b * T_LEN + n * 64);
  // ---- issue gate staging first (consumed in epilogue; drained by syncthreads)
  {
    int row = wave * 2 + (lane >> 5), sc32 = lane & 31;
    #pragma unroll
    for (int c = 0; c < 8; ++c){
      int r = c * 8 + row;
      GLOAD16(g + (rowbase + r) * 2048 + h * 256 + sc32 * 8, &GS[c * 2048 + wave * 512]);
    }
  }
  // ---- Q fragments (reused as P-phase B-operand AND o_inter A-operand)
  s16x8 Qf[4][4];
  #pragma unroll
  for (int rf = 0; rf < 4; ++rf)
    #pragma unroll
    for (int ks = 0; ks < 4; ++ks)
      Qf[rf][ks] = *(const s16x8*)&q[(rowbase + rf * 16 + l15) * 1024 + h * 128 + ks * 32 + lhi * 8];
  // ---- K fragments (P-phase A-operand; wave-specific j rows)
  s16x8 Kf[4];
  #pragma unroll
  for (int ks = 0; ks < 4; ++ks)
    Kf[ks] = *(const s16x8*)&k[(rowbase + wave * 16 + l15) * 1024 + h * 128 + ks * 32 + lhi * 8];
  // ---- P^T = k q'^T : D[j][i]; wave owns j in [16w,16w+16)
  f32x4 accP[4] = {};
  #pragma unroll
  for (int ks = 0; ks < 4; ++ks)
    #pragma unroll
    for (int nf = 0; nf < 4; ++nf)
      accP[nf] = MFMA16(Kf[ks], Qf[nf][ks], accP[nf]);
  const float lg = log2f(1.0f - exp2f(-(float)(5 + h)));
  {
    int jb = wave * 16 + 4 * lhi;
    float dj[4];
    #pragma unroll
    for (int r = 0; r < 4; ++r) dj[r] = exp2f(-(float)(jb + r + 1) * lg);
    #pragma unroll
    for (int nf = 0; nf < 4; ++nf){
      int i = nf * 16 + l15;
      s16x4 pk;
      #pragma unroll
      for (int r = 0; r < 4; ++r)
        pk[r] = f2bf((i >= jb + r) ? accP[nf][r] * dj[r] : 0.0f);
      *(s16x4*)&PS[i * 72 + jb] = pk;
    }
  }
  // ---- o_inter: acc = q'.S (ST fragments streamed global->reg); wave owns e in [64w,64w+64)
  f32x4 acc[4][4] = {};
  if (n){
    size_t stb = (((size_t)n * 4 + b) * 8 + h) * 32768;
    #pragma unroll
    for (int ks = 0; ks < 4; ++ks){
      s16x8 Sf[4];
      #pragma unroll
      for (int nf = 0; nf < 4; ++nf){
        int e = wave * 64 + nf * 16 + l15;
        Sf[nf] = *(const s16x8*)&ST[stb + (size_t)e * 128 + ks * 32 + lhi * 8];
      }
      #pragma unroll
      for (int mf = 0; mf < 4; ++mf)
        #pragma unroll
        for (int nf = 0; nf < 4; ++nf)
          acc[mf][nf] = MFMA16(Qf[mf][ks], Sf[nf], acc[mf][nf]);
    }
  }
  // ---- hoist V fragment loads above the PS barrier (latency hides under barrier wait)
  s16x8 Vf[2][4];
  #pragma unroll
  for (int ks2 = 0; ks2 < 2; ++ks2)
    #pragma unroll
    for (int nf = 0; nf < 4; ++nf){
      int e = wave * 64 + nf * 16 + l15;
      Vf[ks2][nf] = *(const s16x8*)&vT[(size_t)(h * 256 + e) * MROWS + rowbase + ks2 * 32 + lhi * 8];
    }
  __syncthreads();                                   // PS visible (also drains GS staging)
  // ---- o_intra: acc += P v  (P from LDS, V from regs)
  #pragma unroll
  for (int ks2 = 0; ks2 < 2; ++ks2){
    s16x8 Pf[4];
    #pragma unroll
    for (int mf = 0; mf < 4; ++mf)
      Pf[mf] = *(const s16x8*)&PS[(mf * 16 + l15) * 72 + ks2 * 32 + lhi * 8];
    #pragma unroll
    for (int mf = 0; mf < 4; ++mf)
      #pragma unroll
      for (int nf = 0; nf < 4; ++nf)
        acc[mf][nf] = MFMA16(Pf[mf], Vf[ks2][nf], acc[mf][nf]);
  }
  // ---- row-wise sum of squares (over e=256): intra-wave shuffle + cross-wave LDS
  float ssp[4][4];
  #pragma unroll
  for (int mf = 0; mf < 4; ++mf)
    #pragma unroll
    for (int r = 0; r < 4; ++r){
      float s = 0.f;
      #pragma unroll
      for (int nf = 0; nf < 4; ++nf) s += acc[mf][nf][r] * acc[mf][nf][r];
      #pragma unroll
      for (int off = 8; off >= 1; off >>= 1) s += __shfl_xor(s, off, 64);
      ssp[mf][r] = s;
    }
  if (l15 == 0){
    #pragma unroll
    for (int mf = 0; mf < 4; ++mf)
      #pragma unroll
      for (int r = 0; r < 4; ++r){
        int row = mf * 16 + 4 * lhi + r;
        SS[row * 4 + wave] = ssp[mf][r];
      }
  }
  __syncthreads();                                   // SS + GS ready; PS dead (YT aliases it)
  // ---- normalize + gate, write padded y tile
  #pragma unroll
  for (int mf = 0; mf < 4; ++mf){
    float rr[4];
    #pragma unroll
    for (int r = 0; r < 4; ++r){
      int row = mf * 16 + 4 * lhi + r;
      f32x4 s4 = *(const f32x4*)&SS[row * 4];
      float tot = s4[0] + s4[1] + s4[2] + s4[3];
      rr[r] = __builtin_amdgcn_rsqf(tot * (1.0f / 256.0f) + 1e-5f);
    }
    #pragma unroll
    for (int nf = 0; nf < 4; ++nf){
      int e = wave * 64 + nf * 16 + l15;
      float nwe = nw[e];
      #pragma unroll
      for (int r = 0; r < 4; ++r){
        int row = mf * 16 + 4 * lhi + r;
        float gf = bf2f(GS[row * 256 + e]);
        float sig = __builtin_amdgcn_rcpf(1.0f + exp2f(gf * -1.4426950408889634f));
        YT[row * 264 + e] = f2bf(acc[mf][nf][r] * rr[r] * nwe * gf * sig);
      }
    }
  }
  __syncthreads();
  // ---- coalesced copy out
  #pragma unroll
  for (int it = 0; it < 8; ++it){
    int flat = it * 2048 + tid * 8;
    int row = flat >> 8, e = flat & 255;
    s16x8 v = *(const s16x8*)&YT[row * 264 + e];
    *(s16x8*)&y[(rowbase + row) * 2048 + h * 256 + e] = v;
  }
}

// ---------------- host ----------------
extern "C" void kernel_launch(void* const* d_in, const int* in_sizes, int n_in,
                              void* d_out, int out_size, void* d_ws, size_t ws_size,
                              hipStream_t stream){
  const float* x  = (const float*)d_in[0];
  const float* Wq = (const float*)d_in[1];
  const float* Wk = (const float*)d_in[2];
  const float* Wv = (const float*)d_in[3];
  const float* Wg = (const float*)d_in[4];
  const float* Wo = (const float*)d_in[5];
  const float* nw = (const float*)d_in[6];
  float* out = (float*)d_out;

  // workspace layout (208 MiB total).  WT order: q|k|g|v.
  // yb aliases [0, 32MB) = xb + WT + head of kTt — all dead before ret_fused writes it.
  // rope table aliases STb's n=0 slice (scan writes n>=1 only, fused reads n>=1 only).
  char* w = (char*)d_ws;
  short* xb  = (short*)w;               w += (size_t)8192 * 1024 * 2;   // 16 MB
  short* WT  = (short*)w;               w += (size_t)6144 * 1024 * 2;   // 12.6 MB (WqT|WkT|WgT|WvT)
  short* kTt = (short*)w;               w += (size_t)1024 * 8192 * 2;   // 16 MB (dead after ret_scan)
  short* qb  = (short*)w;               w += (size_t)8192 * 1024 * 2;   // 16 MB
  short* kb  = (short*)w;               w += (size_t)8192 * 1024 * 2;   // 16 MB
  short* vT  = (short*)w;               w += (size_t)2048 * 8192 * 2;   // 32 MB
  short* gb  = (short*)w;               w += (size_t)8192 * 2048 * 2;   // 32 MB
  short* STb = (short*)w;               w += (size_t)32 * 4 * 8 * 32768 * 2; // 64 MB
  short* WoT = (short*)w;               w += (size_t)1024 * 2048 * 2;   // 4 MB
  short* yb  = (short*)d_ws;                                            // alias, 32 MB
  float* tab = (float*)STb;                                             // alias, 1 MB (n=0 slice)

  cvt_f32_bf16<<<8192, 256, 0, stream>>>(x, xb, 8192 * 1024 / 4);
  dim3 tb(32, 8);
  tr_w4<<<dim3(192, 32), tb, 0, stream>>>(Wq, Wk, Wv, Wg, WT);
  tr_w <<<dim3(32, 64),  tb, 0, stream>>>(Wo, WoT, 2048, 1024);
  rope_table<<<512, 256, 0, stream>>>(tab);

  // q|k|g projection: [8192][1024] x [4096][1024]^T, swapped-operand packed stores
  gemm256<3><<<512, 512, 0, stream>>>(xb, WT, qb, kb, nullptr, gb, 1024, 16, 16);
  // v projection: [8192][1024] x [2048][1024]^T -> transposed vT [2048][8192]
  gemm256<4><<<256, 512, 0, stream>>>(xb, WT + (size_t)4096 * 1024, nullptr, nullptr, vT, nullptr,
                                      1024, 16, 8);

  rope_q   <<<16384, 256, 0, stream>>>(qb, tab);
  rope_k_tr<<<dim3(128, 8), 256, 0, stream>>>(kb, kTt, tab);

  ret_scan <<<dim3(8, 8, 4),  256, 0, stream>>>(kTt, vT, STb);
  ret_fused<<<dim3(32, 8, 4), 256, 0, stream>>>(qb, kb, vT, STb, gb, nw, yb);

  // out-projection: [8192][2048] x [1024][2048]^T -> f32 [8192][1024], BM=128, full grid
  gemm256<2><<<256, 512, 0, stream>>>(yb, WoT, out, nullptr, nullptr, nullptr, 2048, 32, 4);
}

// Round 18
// 275.851 us; speedup vs baseline: 1.0356x; 1.0174x over previous
//
#include <hip/hip_runtime.h>
#include <hip/hip_bf16.h>
#include <cstdint>
#include <cstddef>

using f32x4 = __attribute__((ext_vector_type(4))) float;
using s16x8 = __attribute__((ext_vector_type(8))) short;
using s16x4 = __attribute__((ext_vector_type(4))) short;

#define DEVINL __device__ __forceinline__

static constexpr int T_LEN  = 2048;
static constexpr int MROWS  = 8192;   // B*T
static constexpr int NCHUNK = 32;     // T / 64

DEVINL float bf2f(short s){
  unsigned u = ((unsigned)(unsigned short)s) << 16;
  return __builtin_bit_cast(float, u);
}
DEVINL short f2bf(float f){
  unsigned u = __builtin_bit_cast(unsigned, f);
  u = (u + 0x7fffu + ((u >> 16) & 1u)) >> 16;
  return (short)(unsigned short)u;
}

// async global->LDS, 16B per lane; LDS dest must be wave-uniform base (+lane*16 implicit)
#define GLOAD16(gp, lp) \
  __builtin_amdgcn_global_load_lds((__attribute__((address_space(1))) void*)(gp), \
                                   (__attribute__((address_space(3))) void*)(lp), 16, 0, 0)

#define MFMA16(a, b, c) __builtin_amdgcn_mfma_f32_16x16x32_bf16((a), (b), (c), 0, 0, 0)
#define SBAR()  __builtin_amdgcn_sched_barrier(0)
#define WAITVM(n)   asm volatile("s_waitcnt vmcnt(" #n ")" ::: "memory")

// ---------------- elementwise f32 -> bf16 ----------------
__global__ __launch_bounds__(256) void cvt_f32_bf16(const float* __restrict__ in,
                                                    short* __restrict__ out, int n4){
  int i = blockIdx.x * 256 + threadIdx.x;
  if (i >= n4) return;
  float4 v = ((const float4*)in)[i];
  short4 o;
  o.x = f2bf(v.x); o.y = f2bf(v.y); o.z = f2bf(v.z); o.w = f2bf(v.w);
  ((short4*)out)[i] = o;
}

// ---------------- transpose f32 [R][C] -> bf16 [C][R] ----------------
__global__ __launch_bounds__(256) void tr_w(const float* __restrict__ in,
                                            short* __restrict__ out, int R, int C){
  __shared__ float tile[32][33];
  int c0 = blockIdx.x * 32, r0 = blockIdx.y * 32;
  int tx = threadIdx.x, ty = threadIdx.y;           // (32,8)
  #pragma unroll
  for (int i = 0; i < 4; ++i){
    int r = ty + i * 8;
    tile[r][tx] = in[(size_t)(r0 + r) * C + c0 + tx];
  }
  __syncthreads();
  #pragma unroll
  for (int i = 0; i < 4; ++i){
    int c = ty + i * 8;
    out[(size_t)(c0 + c) * R + r0 + tx] = f2bf(tile[tx][c]);
  }
}

// --------- merged transpose of the 4 projection weights into WT (q|k|g|v), all R=1024 ---------
__global__ __launch_bounds__(256) void tr_w4(const float* __restrict__ Wq,
                                             const float* __restrict__ Wk,
                                             const float* __restrict__ Wv,
                                             const float* __restrict__ Wg,
                                             short* __restrict__ WT){
  __shared__ float tile[32][33];
  int bx = blockIdx.x;
  const float* src; int C; size_t off; int cb;
  if (bx < 32)       { src = Wq; C = 1024; off = 0;                       cb = bx; }
  else if (bx < 64)  { src = Wk; C = 1024; off = (size_t)1024 * 1024;     cb = bx - 32; }
  else if (bx < 128) { src = Wg; C = 2048; off = (size_t)2048 * 1024;     cb = bx - 64; }
  else               { src = Wv; C = 2048; off = (size_t)4096 * 1024;     cb = bx - 128; }
  int c0 = cb * 32, r0 = blockIdx.y * 32;
  int tx = threadIdx.x, ty = threadIdx.y;           // (32,8)
  #pragma unroll
  for (int i = 0; i < 4; ++i){
    int r = ty + i * 8;
    tile[r][tx] = src[(size_t)(r0 + r) * C + c0 + tx];
  }
  __syncthreads();
  #pragma unroll
  for (int i = 0; i < 4; ++i){
    int c = ty + i * 8;
    WT[off + (size_t)(c0 + c) * 1024 + r0 + tx] = f2bf(tile[tx][c]);
  }
}

// ---------------- rope cos/sin table [2048][64] float2 ----------------
__global__ __launch_bounds__(256) void rope_table(float* __restrict__ tab){
  int i = blockIdx.x * 256 + threadIdx.x;           // t*64+d, 131072 total
  int t = i >> 6, d = i & 63;
  float inv = exp2f(-(float)d * (13.287712379549449f / 64.0f));  // 10000^(-d/64)
  float f = (float)t * inv;
  float s, c;
  sincosf(f, &s, &c);
  tab[2 * i]     = c;
  tab[2 * i + 1] = s;
}

// ------- RoPE in-place on q; bakes DK^-0.5 * gamma^((t%64)+1) -------
__global__ __launch_bounds__(256) void rope_q(short* __restrict__ qb,
                                              const float* __restrict__ tab){
  int idx = blockIdx.x * 256 + threadIdx.x;         // 8192 * 512 threads
  int bt  = idx >> 9, rem = idx & 511;
  int h   = rem >> 6, d = rem & 63;
  int t   = bt & (T_LEN - 1);
  float2 cs = ((const float2*)tab)[t * 64 + d];
  float lg = log2f(1.0f - exp2f(-(float)(5 + h)));
  float mult = 0.08838834764831845f * exp2f((float)((t & 63) + 1) * lg);  // DK^-0.5 * gamma^(i+1)
  size_t base = (size_t)bt * 1024 + h * 128 + d;
  float x1 = bf2f(qb[base]), x2 = bf2f(qb[base + 64]);
  qb[base]      = f2bf((x1 * cs.x - x2 * cs.y) * mult);
  qb[base + 64] = f2bf((x2 * cs.x + x1 * cs.y) * mult);
}

// ------- fused RoPE(k) in-place + decay-baked transpose kb -> kTt [1024][8192] -------
// grid (128 bt-chunks, 8 heads), 256 thr. Tile = 64 bt rows x 128 d cols (one head).
// kb gets roped values (no decay); kTt[(h*128+d)][bt] gets roped * gamma^(63-j), j = bt%64 = r.
__global__ __launch_bounds__(256) void rope_k_tr(short* __restrict__ kb,
                                                 short* __restrict__ kTt,
                                                 const float* __restrict__ tab){
  __shared__ alignas(16) short T[64 * 128];          // staging tile [r][d]
  __shared__ alignas(16) short U[128 * 68];          // transposed [d][r], ld 68 (bank spread)
  const int tid = threadIdx.x, wave = tid >> 6, lane = tid & 63;
  const int bt0 = blockIdx.x * 64, h = blockIdx.y;
  const float lg = log2f(1.0f - exp2f(-(float)(5 + h)));
  // ---- stage: 64 rows x 256B, 4 gload calls (linear dest)
  #pragma unroll
  for (int c = 0; c < 4; ++c){
    int rbase = c * 16 + wave * 4;
    GLOAD16(kb + (size_t)(bt0 + rbase + (lane >> 4)) * 1024 + h * 128 + (lane & 15) * 8,
            T + rbase * 128);
  }
  WAITVM(0);
  __syncthreads();
  // ---- rope: thread owns (r = tid>>2, d in [ (tid&3)*16, +16 )); writes kb + U
  {
    int r = tid >> 2, dbase = (tid & 3) * 16;
    int t = (bt0 + r) & (T_LEN - 1);
    float dec = exp2f((float)(63 - r) * lg);
    s16x8 lo[2], hi[2];
    #pragma unroll
    for (int i = 0; i < 16; ++i){
      int d = dbase + i;
      float2 cs = ((const float2*)tab)[t * 64 + d];
      float x1 = bf2f(T[r * 128 + d]);
      float x2 = bf2f(T[r * 128 + 64 + d]);
      float y1 = x1 * cs.x - x2 * cs.y;
      float y2 = x2 * cs.x + x1 * cs.y;
      lo[i >> 3][i & 7] = f2bf(y1);
      hi[i >> 3][i & 7] = f2bf(y2);
      U[(d)      * 68 + r] = f2bf(y1 * dec);
      U[(d + 64) * 68 + r] = f2bf(y2 * dec);
    }
    size_t gb = (size_t)(bt0 + r) * 1024 + h * 128 + dbase;
    *(s16x8*)&kb[gb]          = lo[0];
    *(s16x8*)&kb[gb + 8]      = lo[1];
    *(s16x8*)&kb[gb + 64]     = hi[0];
    *(s16x8*)&kb[gb + 64 + 8] = hi[1];
  }
  __syncthreads();
  // ---- kTt write: thread owns (d = tid>>1, half = tid&1): 32 bt contiguous (64B)
  {
    int d = tid >> 1, half = tid & 1;
    const short* src = &U[d * 68 + half * 32];
    size_t gb = (size_t)(h * 128 + d) * MROWS + bt0 + half * 32;
    #pragma unroll
    for (int c = 0; c < 8; ++c)
      *(s16x4*)&kTt[gb + c * 4] = *(const s16x4*)&src[c * 4];
  }
}

// ======= half-tile GEMM: BK=64, 8 waves, 2 raw barriers/tile, compiler-scheduled ds_reads =======
// C[m][n] = sum_k A[m][k] * Bt[n][k].
// Per tile: [rdB + rdA(half0) ; stageA(t+2) ; 32 MFMA ; s_barrier(mid) ; stageB(t+2) ;
//            rdA(half1) ; 32 MFMA ; vmcnt(counted) ; s_barrier(end)]
// MODE 2: BM=128, swapped operands, f32 row-major out (N=1024) -> float4 stores, o0.
// MODE 3: BM=256, swapped operands, q|k|g bf16 row-major packed s16x4 stores (N=4096).
// MODE 4: BM=256, normal operands, v transposed out [2048][8192] packed s16x4 col stores, o2.
DEVINL s16x8 frag64(const short* buf, int row, int ks, int lhi){
  int ch = (ks * 4 + lhi) ^ (row & 7);
  return *(const s16x8*)&buf[row * 64 + ch * 8];
}

template<int MODE>
__global__ __launch_bounds__(512, 2) void gemm256(const short* __restrict__ A,
                                                  const short* __restrict__ Bt,
                                                  void* __restrict__ o0, void* __restrict__ o1,
                                                  void* __restrict__ o2, void* __restrict__ o3,
                                                  int K, int nt, int NT){
  constexpr int BM   = (MODE == 2 ? 128 : 256);
  constexpr int ABUF = BM * 64;                     // shorts per A buffer
  constexpr int MF   = BM / 32;                     // acc rows per wave (4 or 8)
  constexpr int MH   = MF / 2;                      // acc rows per half (2 or 4)
  __shared__ alignas(16) short LBUF[3 * ABUF + 2 * 16384];
  short* const BB = LBUF + 3 * ABUF;
  const int tid = threadIdx.x, wave = tid >> 6, lane = tid & 63;
  const int l15 = lane & 15, lhi = lane >> 4;
  const int wm = (wave >> 2) * (BM / 2), wn = (wave & 3) * 64;
  // XCD group-major swizzle: per XCD walk m within group of MG (A stays L2-resident), n outer
  const int MG  = (gridDim.x >> 3) / NT;
  const int xcd = blockIdx.x & 7, idx = blockIdx.x >> 3;
  const int mi  = idx % MG, nn = idx / MG;
  const int m0  = (xcd * MG + mi) * BM, n0 = nn * 256;
  const short* Ag = A + (size_t)m0 * K;
  const short* Bg = Bt + (size_t)n0 * K;
  const int sr = lane >> 3;
  const int gc = ((lane & 7) ^ sr) * 8;             // pre-swizzled source chunk
  f32x4 acc[MF][4] = {};

  auto stageA = [&](int t, int half){
    short* lb = LBUF + (t % 3) * ABUF;
    size_t k0 = (size_t)t * 64;
    if constexpr (BM == 256){
      #pragma unroll
      for (int c = 0; c < 2; ++c){
        int r0 = half * 128 + c * 64;
        GLOAD16(Ag + (size_t)(r0 + wave * 8 + sr) * K + k0 + gc, lb + (r0 + wave * 8) * 64);
      }
    } else {
      int r0 = half * 64;
      GLOAD16(Ag + (size_t)(r0 + wave * 8 + sr) * K + k0 + gc, lb + (r0 + wave * 8) * 64);
    }
  };
  auto stageB = [&](int t, int half){
    short* lb = BB + (t & 1) * 16384;
    size_t k0 = (size_t)t * 64;
    #pragma unroll
    for (int c = 0; c < 2; ++c){
      int r0 = half * 128 + c * 64;
      GLOAD16(Bg + (size_t)(r0 + wave * 8 + sr) * K + k0 + gc, lb + (r0 + wave * 8) * 64);
    }
  };

  // ---- prologue: stage tiles 0 and 1; drain tile0, keep tile1 in flight
  stageA(0, 0); stageA(0, 1); stageB(0, 0); stageB(0, 1);
  stageA(1, 0); stageA(1, 1); stageB(1, 0); stageB(1, 1);
  if constexpr (BM == 256) WAITVM(8); else WAITVM(6);
  __builtin_amdgcn_s_barrier();

  for (int t = 0; t < nt; ++t){
    const short* Ab = LBUF + (t % 3) * ABUF;
    const short* Bb = BB + (t & 1) * 16384;
    s16x8 bfr[2][4];
    s16x8 af[MH][2];
    // ---- first half: read B (whole tile) + A rows [0, MH); MFMA overlaps read drain
    #pragma unroll
    for (int ks = 0; ks < 2; ++ks)
      #pragma unroll
      for (int nf = 0; nf < 4; ++nf)
        bfr[ks][nf] = frag64(Bb, wn + nf * 16 + l15, ks, lhi);
    #pragma unroll
    for (int i = 0; i < MH; ++i)
      #pragma unroll
      for (int ks = 0; ks < 2; ++ks)
        af[i][ks] = frag64(Ab, wm + i * 16 + l15, ks, lhi);
    if (t + 2 < nt){ stageA(t + 2, 0); stageA(t + 2, 1); }
    __builtin_amdgcn_s_setprio(1);
    #pragma unroll
    for (int ks = 0; ks < 2; ++ks)
      #pragma unroll
      for (int i = 0; i < MH; ++i)
        #pragma unroll
        for (int nf = 0; nf < 4; ++nf){
          if constexpr (MODE == 4)
            acc[i][nf] = MFMA16(af[i][ks], bfr[ks][nf], acc[i][nf]);
          else
            acc[i][nf] = MFMA16(bfr[ks][nf], af[i][ks], acc[i][nf]);
        }
    __builtin_amdgcn_s_setprio(0);
    __builtin_amdgcn_s_barrier();                   // mid: all waves' B(t)/A-half0 regs populated
    // ---- second half: stageB(t+2) now safe; read A rows [MH, MF)
    if (t + 2 < nt){ stageB(t + 2, 0); stageB(t + 2, 1); }
    #pragma unroll
    for (int i = 0; i < MH; ++i)
      #pragma unroll
      for (int ks = 0; ks < 2; ++ks)
        af[i][ks] = frag64(Ab, wm + (MH + i) * 16 + l15, ks, lhi);
    __builtin_amdgcn_s_setprio(1);
    #pragma unroll
    for (int ks = 0; ks < 2; ++ks)
      #pragma unroll
      for (int i = 0; i < MH; ++i)
        #pragma unroll
        for (int nf = 0; nf < 4; ++nf){
          if constexpr (MODE == 4)
            acc[MH + i][nf] = MFMA16(af[i][ks], bfr[ks][nf], acc[MH + i][nf]);
          else
            acc[MH + i][nf] = MFMA16(bfr[ks][nf], af[i][ks], acc[MH + i][nf]);
        }
    __builtin_amdgcn_s_setprio(0);
    if (t < nt - 2){
      if constexpr (BM == 256) WAITVM(8); else WAITVM(6);   // t+1 fully landed
    } else if (t == nt - 2){
      WAITVM(0);
    }
    __builtin_amdgcn_s_barrier();                   // end: tile t+1 visible to all
  }
  // ---- epilogue (packed stores)
  if constexpr (MODE == 2){
    // swapped: lane's 4 accs = 4 consecutive cols of one row -> float4
    float* dst = (float*)o0;
    #pragma unroll
    for (int mf = 0; mf < MF; ++mf){
      int m = m0 + wm + mf * 16 + l15;
      #pragma unroll
      for (int nf = 0; nf < 4; ++nf){
        int nb = n0 + wn + nf * 16 + 4 * lhi;
        *(float4*)&dst[(size_t)m * 1024 + nb] = *(float4*)&acc[mf][nf];
      }
    }
  } else if constexpr (MODE == 4){
    // normal order: v transposed out [2048][8192]; lane's 4 accs = 4 consecutive rows
    short* dst = (short*)o2;
    #pragma unroll
    for (int mf = 0; mf < MF; ++mf){
      int rb = m0 + wm + mf * 16 + 4 * lhi;
      #pragma unroll
      for (int nf = 0; nf < 4; ++nf){
        int e = n0 + wn + nf * 16 + l15;
        s16x4 pk;
        #pragma unroll
        for (int r = 0; r < 4; ++r) pk[r] = f2bf(acc[mf][nf][r]);
        *(s16x4*)&dst[(size_t)e * MROWS + rb] = pk;
      }
    }
  } else {
    // swapped: q/k/g row-major; lane's 4 accs = 4 consecutive cols of one row
    short* dst; int ld, cb;
    if (n0 < 1024)      { dst = (short*)o0; ld = 1024; cb = n0; }
    else if (n0 < 2048) { dst = (short*)o1; ld = 1024; cb = n0 - 1024; }
    else                { dst = (short*)o3; ld = 2048; cb = n0 - 2048; }
    #pragma unroll
    for (int mf = 0; mf < MF; ++mf){
      int m = m0 + wm + mf * 16 + l15;
      #pragma unroll
      for (int nf = 0; nf < 4; ++nf){
        int nb = cb + wn + nf * 16 + 4 * lhi;
        s16x4 pk;
        #pragma unroll
        for (int r = 0; r < 4; ++r) pk[r] = f2bf(acc[mf][nf][r]);
        *(s16x4*)&dst[(size_t)m * ld + nb] = pk;
      }
    }
  }
}

// ---------------- retention state scan: S in MFMA accumulators, write bf16 ST[n] snapshots ----------------
// grid (16=db*eb, 8, 4); 256 thr; 2 blocks/CU. Block owns d-range 64 (db) x e-range 32 (eb 0..7).
// Per chunk: 3 gload_lds (kT x2, vT x1) + 2 snapshot stores; counted vmcnt re-derived for 3/2:
//   n=0 -> 6 (S1+S2 newer), steady -> 7 (stores(n-1)+S(n+2)+stores(n)), n=30 -> 4, n=31 -> 2.
__global__ __launch_bounds__(256) void ret_scan(const short* __restrict__ kT,
                                                const short* __restrict__ vT,
                                                short* __restrict__ ST){
  __shared__ alignas(16) short kbuf[3][4096];        // 64 x 64
  __shared__ alignas(16) short vbuf[3][2048];        // 32 x 64
  const int tid = threadIdx.x, wave = tid >> 6, lane = tid & 63;
  const int db = blockIdx.x & 1, eb = blockIdx.x >> 1;
  const int h = blockIdx.y, b = blockIdx.z;
  const int d0 = db * 64, e0 = eb * 32;
  const float lg = log2f(1.0f - exp2f(-(float)(5 + h)));
  const float gC = exp2f(64.0f * lg);
  f32x4 Sacc[2] = {};
  const int srow = wave * 8 + (lane >> 3);           // 0..31
  const int sc   = lane & 7;

  auto STAGE = [&](int n, int buf){
    size_t rowbase = (size_t)(b * T_LEN + n * 64);
    #pragma unroll
    for (int c = 0; c < 2; ++c){
      int r = c * 32 + srow;
      int gc2 = sc ^ (r & 7);
      GLOAD16(kT + (size_t)(h * 128 + d0 + r) * MROWS + rowbase + gc2 * 8,
              &kbuf[buf][c * 2048 + wave * 512]);
    }
    {
      int r = srow;
      int gc2 = sc ^ (r & 7);
      GLOAD16(vT + (size_t)(h * 256 + e0 + r) * MROWS + rowbase + gc2 * 8,
              &vbuf[buf][wave * 512]);
    }
  };

  STAGE(0, 0);
  STAGE(1, 1);
  for (int n = 0; n < NCHUNK; ++n){
    const int buf = n % 3;
    if (n + 2 < NCHUNK) STAGE(n + 2, (n + 2) % 3);      // 3 loads
    if (n > 0){                                          // 2 stores (snapshot BEFORE this chunk)
      size_t stb = (((size_t)n * 4 + b) * 8 + h) * 32768;
      int dbase = d0 + 16 * wave + 4 * (lane >> 4);
      #pragma unroll
      for (int nf = 0; nf < 2; ++nf){
        int e = e0 + nf * 16 + (lane & 15);
        s16x4 pk;
        #pragma unroll
        for (int r = 0; r < 4; ++r) pk[r] = f2bf(Sacc[nf][r]);
        *(s16x4*)&ST[stb + (size_t)e * 128 + dbase] = pk;
      }
    }
    // counted vmcnt: guarantee chunk-n loads complete; newer loads/stores stay outstanding
    if (n == 0)       WAITVM(6);
    else if (n < 30)  WAITVM(7);
    else if (n == 30) WAITVM(4);
    else              WAITVM(2);
    __builtin_amdgcn_s_barrier();
    SBAR();
    #pragma unroll
    for (int nf = 0; nf < 2; ++nf)
      #pragma unroll
      for (int r = 0; r < 4; ++r) Sacc[nf][r] *= gC;
    #pragma unroll
    for (int ks = 0; ks < 2; ++ks){
      int d = 16 * wave + (lane & 15);
      int chA = (ks * 4 + (lane >> 4)) ^ (d & 7);
      s16x8 af = *(const s16x8*)&kbuf[buf][d * 64 + chA * 8];
      #pragma unroll
      for (int nf = 0; nf < 2; ++nf){
        int e = nf * 16 + (lane & 15);
        int chB = (ks * 4 + (lane >> 4)) ^ (e & 7);
        s16x8 bv = *(const s16x8*)&vbuf[buf][e * 64 + chB * 8];
        Sacc[nf] = MFMA16(af, bv, Sacc[nf]);
      }
    }
    __builtin_amdgcn_s_barrier();
    SBAR();
  }
}

// ---------------- fused per-chunk retention + RMS-norm + SiLU gate (reg-direct) ----------------
__global__ __launch_bounds__(256, 2) void ret_fused(const short* __restrict__ q,
                                                    const short* __restrict__ k,
                                                    const short* __restrict__ vT,
                                                    const short* __restrict__ ST,
                                                    const short* __restrict__ g,
                                                    const float* __restrict__ nw,
                                                    short* __restrict__ y){
  __shared__ alignas(16) short GS[16384];             // gate tile [64][256]
  __shared__ alignas(16) float SS[256];               // cross-wave sum-of-squares
  __shared__ alignas(16) short XS[16896];             // phase1: PS [64][72]; phase2: YT [64][264]
  short* PS = XS;
  short* YT = XS;
  const int tid = threadIdx.x, wave = tid >> 6, lane = tid & 63;
  const int l15 = lane & 15, lhi = lane >> 4;
  const int n = blockIdx.x, h = blockIdx.y, b = blockIdx.z;
  const size_t rowbase = (size_t)(b * T_LEN + n * 64);
  // ---- issue gate staging first (consumed in epilogue; drained by syncthreads)
  {
    int row = wave * 2 + (lane >> 5), sc32 = lane & 31;
    #pragma unroll
    for (int c = 0; c < 8; ++c){
      int r = c * 8 + row;
      GLOAD16(g + (rowbase + r) * 2048 + h * 256 + sc32 * 8, &GS[c * 2048 + wave * 512]);
    }
  }
  // ---- Q fragments (reused as P-phase B-operand AND o_inter A-operand)
  s16x8 Qf[4][4];
  #pragma unroll
  for (int rf = 0; rf < 4; ++rf)
    #pragma unroll
    for (int ks = 0; ks < 4; ++ks)
      Qf[rf][ks] = *(const s16x8*)&q[(rowbase + rf * 16 + l15) * 1024 + h * 128 + ks * 32 + lhi * 8];
  // ---- K fragments (P-phase A-operand; wave-specific j rows)
  s16x8 Kf[4];
  #pragma unroll
  for (int ks = 0; ks < 4; ++ks)
    Kf[ks] = *(const s16x8*)&k[(rowbase + wave * 16 + l15) * 1024 + h * 128 + ks * 32 + lhi * 8];
  // ---- P^T = k q'^T : D[j][i]; wave owns j in [16w,16w+16)
  f32x4 accP[4] = {};
  #pragma unroll
  for (int ks = 0; ks < 4; ++ks)
    #pragma unroll
    for (int nf = 0; nf < 4; ++nf)
      accP[nf] = MFMA16(Kf[ks], Qf[nf][ks], accP[nf]);
  const float lg = log2f(1.0f - exp2f(-(float)(5 + h)));
  {
    int jb = wave * 16 + 4 * lhi;
    float dj[4];
    #pragma unroll
    for (int r = 0; r < 4; ++r) dj[r] = exp2f(-(float)(jb + r + 1) * lg);
    #pragma unroll
    for (int nf = 0; nf < 4; ++nf){
      int i = nf * 16 + l15;
      s16x4 pk;
      #pragma unroll
      for (int r = 0; r < 4; ++r)
        pk[r] = f2bf((i >= jb + r) ? accP[nf][r] * dj[r] : 0.0f);
      *(s16x4*)&PS[i * 72 + jb] = pk;
    }
  }
  // ---- o_inter: acc = q'.S (ST fragments streamed global->reg); wave owns e in [64w,64w+64)
  f32x4 acc[4][4] = {};
  if (n){
    size_t stb = (((size_t)n * 4 + b) * 8 + h) * 32768;
    #pragma unroll
    for (int ks = 0; ks < 4; ++ks){
      s16x8 Sf[4];
      #pragma unroll
      for (int nf = 0; nf < 4; ++nf){
        int e = wave * 64 + nf * 16 + l15;
        Sf[nf] = *(const s16x8*)&ST[stb + (size_t)e * 128 + ks * 32 + lhi * 8];
      }
      #pragma unroll
      for (int mf = 0; mf < 4; ++mf)
        #pragma unroll
        for (int nf = 0; nf < 4; ++nf)
          acc[mf][nf] = MFMA16(Qf[mf][ks], Sf[nf], acc[mf][nf]);
    }
  }
  // ---- hoist V fragment loads above the PS barrier (latency hides under barrier wait)
  s16x8 Vf[2][4];
  #pragma unroll
  for (int ks2 = 0; ks2 < 2; ++ks2)
    #pragma unroll
    for (int nf = 0; nf < 4; ++nf){
      int e = wave * 64 + nf * 16 + l15;
      Vf[ks2][nf] = *(const s16x8*)&vT[(size_t)(h * 256 + e) * MROWS + rowbase + ks2 * 32 + lhi * 8];
    }
  __syncthreads();                                   // PS visible (also drains GS staging)
  // ---- o_intra: acc += P v  (P from LDS, V from regs)
  #pragma unroll
  for (int ks2 = 0; ks2 < 2; ++ks2){
    s16x8 Pf[4];
    #pragma unroll
    for (int mf = 0; mf < 4; ++mf)
      Pf[mf] = *(const s16x8*)&PS[(mf * 16 + l15) * 72 + ks2 * 32 + lhi * 8];
    #pragma unroll
    for (int mf = 0; mf < 4; ++mf)
      #pragma unroll
      for (int nf = 0; nf < 4; ++nf)
        acc[mf][nf] = MFMA16(Pf[mf], Vf[ks2][nf], acc[mf][nf]);
  }
  // ---- row-wise sum of squares (over e=256): intra-wave shuffle + cross-wave LDS
  float ssp[4][4];
  #pragma unroll
  for (int mf = 0; mf < 4; ++mf)
    #pragma unroll
    for (int r = 0; r < 4; ++r){
      float s = 0.f;
      #pragma unroll
      for (int nf = 0; nf < 4; ++nf) s += acc[mf][nf][r] * acc[mf][nf][r];
      #pragma unroll
      for (int off = 8; off >= 1; off >>= 1) s += __shfl_xor(s, off, 64);
      ssp[mf][r] = s;
    }
  if (l15 == 0){
    #pragma unroll
    for (int mf = 0; mf < 4; ++mf)
      #pragma unroll
      for (int r = 0; r < 4; ++r){
        int row = mf * 16 + 4 * lhi + r;
        SS[row * 4 + wave] = ssp[mf][r];
      }
  }
  __syncthreads();                                   // SS + GS ready; PS dead (YT aliases it)
  // ---- normalize + gate, write padded y tile
  #pragma unroll
  for (int mf = 0; mf < 4; ++mf){
    float rr[4];
    #pragma unroll
    for (int r = 0; r < 4; ++r){
      int row = mf * 16 + 4 * lhi + r;
      f32x4 s4 = *(const f32x4*)&SS[row * 4];
      float tot = s4[0] + s4[1] + s4[2] + s4[3];
      rr[r] = __builtin_amdgcn_rsqf(tot * (1.0f / 256.0f) + 1e-5f);
    }
    #pragma unroll
    for (int nf = 0; nf < 4; ++nf){
      int e = wave * 64 + nf * 16 + l15;
      float nwe = nw[e];
      #pragma unroll
      for (int r = 0; r < 4; ++r){
        int row = mf * 16 + 4 * lhi + r;
        float gf = bf2f(GS[row * 256 + e]);
        float sig = __builtin_amdgcn_rcpf(1.0f + exp2f(gf * -1.4426950408889634f));
        YT[row * 264 + e] = f2bf(acc[mf][nf][r] * rr[r] * nwe * gf * sig);
      }
    }
  }
  __syncthreads();
  // ---- coalesced copy out
  #pragma unroll
  for (int it = 0; it < 8; ++it){
    int flat = it * 2048 + tid * 8;
    int row = flat >> 8, e = flat & 255;
    s16x8 v = *(const s16x8*)&YT[row * 264 + e];
    *(s16x8*)&y[(rowbase + row) * 2048 + h * 256 + e] = v;
  }
}

// ---------------- host ----------------
extern "C" void kernel_launch(void* const* d_in, const int* in_sizes, int n_in,
                              void* d_out, int out_size, void* d_ws, size_t ws_size,
                              hipStream_t stream){
  const float* x  = (const float*)d_in[0];
  const float* Wq = (const float*)d_in[1];
  const float* Wk = (const float*)d_in[2];
  const float* Wv = (const float*)d_in[3];
  const float* Wg = (const float*)d_in[4];
  const float* Wo = (const float*)d_in[5];
  const float* nw = (const float*)d_in[6];
  float* out = (float*)d_out;

  // workspace layout (208 MiB total).  WT order: q|k|g|v.
  // yb aliases [0, 32MB) = xb + WT + head of kTt — all dead before ret_fused writes it.
  // rope table aliases STb's n=0 slice (scan writes n>=1 only, fused reads n>=1 only).
  char* w = (char*)d_ws;
  short* xb  = (short*)w;               w += (size_t)8192 * 1024 * 2;   // 16 MB
  short* WT  = (short*)w;               w += (size_t)6144 * 1024 * 2;   // 12.6 MB (WqT|WkT|WgT|WvT)
  short* kTt = (short*)w;               w += (size_t)1024 * 8192 * 2;   // 16 MB (dead after ret_scan)
  short* qb  = (short*)w;               w += (size_t)8192 * 1024 * 2;   // 16 MB
  short* kb  = (short*)w;               w += (size_t)8192 * 1024 * 2;   // 16 MB
  short* vT  = (short*)w;               w += (size_t)2048 * 8192 * 2;   // 32 MB
  short* gb  = (short*)w;               w += (size_t)8192 * 2048 * 2;   // 32 MB
  short* STb = (short*)w;               w += (size_t)32 * 4 * 8 * 32768 * 2; // 64 MB
  short* WoT = (short*)w;               w += (size_t)1024 * 2048 * 2;   // 4 MB
  short* yb  = (short*)d_ws;                                            // alias, 32 MB
  float* tab = (float*)STb;                                             // alias, 1 MB (n=0 slice)

  cvt_f32_bf16<<<8192, 256, 0, stream>>>(x, xb, 8192 * 1024 / 4);
  dim3 tb(32, 8);
  tr_w4<<<dim3(192, 32), tb, 0, stream>>>(Wq, Wk, Wv, Wg, WT);
  tr_w <<<dim3(32, 64),  tb, 0, stream>>>(Wo, WoT, 2048, 1024);
  rope_table<<<512, 256, 0, stream>>>(tab);

  // q|k|g projection: [8192][1024] x [4096][1024]^T, swapped-operand packed stores
  gemm256<3><<<512, 512, 0, stream>>>(xb, WT, qb, kb, nullptr, gb, 1024, 16, 16);
  // v projection: [8192][1024] x [2048][1024]^T -> transposed vT [2048][8192]
  gemm256<4><<<256, 512, 0, stream>>>(xb, WT + (size_t)4096 * 1024, nullptr, nullptr, vT, nullptr,
                                      1024, 16, 8);

  rope_q   <<<16384, 256, 0, stream>>>(qb, tab);
  rope_k_tr<<<dim3(128, 8), 256, 0, stream>>>(kb, kTt, tab);

  ret_scan <<<dim3(16, 8, 4), 256, 0, stream>>>(kTt, vT, STb);
  ret_fused<<<dim3(32, 8, 4), 256, 0, stream>>>(qb, kb, vT, STb, gb, nw, yb);

  // out-projection: [8192][2048] x [1024][2048]^T -> f32 [8192][1024], BM=128, full grid
  gemm256<2><<<256, 512, 0, stream>>>(yb, WoT, out, nullptr, nullptr, nullptr, 2048, 32, 4);
}